// Round 1
// baseline (4202.908 us; speedup 1.0000x reference)
//
#include <hip/hip_runtime.h>
#include <math.h>

// Problem constants
#define B_    8
#define SEQ   1569      // 1 + 196*8
#define DIMX  768
#define H_    12
#define D3    192       // head dim (3*DH)
#define F_    8
#define NP    196
#define P1    195       // patches kept per frame (p=1..195)
#define NCOL  2304      // 3*DIM
#define RSCALE (1.0f/96.0f)

// ---------------- block reduction helpers (blockDim == 256) ----------------
__device__ __forceinline__ float block_max256(float v, float* red) {
  #pragma unroll
  for (int o = 32; o > 0; o >>= 1) v = fmaxf(v, __shfl_xor(v, o, 64));
  __syncthreads();
  if ((threadIdx.x & 63) == 0) red[threadIdx.x >> 6] = v;
  __syncthreads();
  return fmaxf(fmaxf(red[0], red[1]), fmaxf(red[2], red[3]));
}

__device__ __forceinline__ float block_sum256(float v, float* red) {
  #pragma unroll
  for (int o = 32; o > 0; o >>= 1) v += __shfl_xor(v, o, 64);
  __syncthreads();
  if ((threadIdx.x & 63) == 0) red[threadIdx.x >> 6] = v;
  __syncthreads();
  return red[0] + red[1] + red[2] + red[3];
}

// ---------------- generic fp32 GEMM: C = A@W + bias ----------------
// A: M x K row-major, W: K x N row-major, bias: N, C: M x N.
// Requires K % 16 == 0, N % 64 == 0. M arbitrary.
__global__ __launch_bounds__(256) void gemm_bias_kernel(
    const float* __restrict__ A, const float* __restrict__ W,
    const float* __restrict__ bias, float* __restrict__ C,
    int M, int N, int K) {
  __shared__ float As[16][64];   // As[k][m]
  __shared__ float Bs[16][64];   // Bs[k][n]
  const int tid  = threadIdx.x;
  const int row0 = blockIdx.x * 64;
  const int col0 = blockIdx.y * 64;
  const int tx = tid & 15, ty = tid >> 4;

  const int am = tid >> 2;           // 0..63
  const int ak = (tid & 3) * 4;      // 0,4,8,12
  const int bk = tid >> 4;           // 0..15
  const int bc = (tid & 15) * 4;     // 0..60

  float acc[4][4] = {{0.f,0.f,0.f,0.f},{0.f,0.f,0.f,0.f},
                     {0.f,0.f,0.f,0.f},{0.f,0.f,0.f,0.f}};

  for (int k0 = 0; k0 < K; k0 += 16) {
    float4 a4 = make_float4(0.f, 0.f, 0.f, 0.f);
    const int arow = row0 + am;
    if (arow < M) a4 = *(const float4*)(A + (size_t)arow * K + k0 + ak);
    As[ak + 0][am] = a4.x; As[ak + 1][am] = a4.y;
    As[ak + 2][am] = a4.z; As[ak + 3][am] = a4.w;

    const float4 b4 = *(const float4*)(W + (size_t)(k0 + bk) * N + col0 + bc);
    *(float4*)&Bs[bk][bc] = b4;
    __syncthreads();

    #pragma unroll
    for (int kk = 0; kk < 16; ++kk) {
      const float4 av = *(const float4*)&As[kk][ty * 4];
      const float4 bv = *(const float4*)&Bs[kk][tx * 4];
      const float ar[4] = {av.x, av.y, av.z, av.w};
      const float br[4] = {bv.x, bv.y, bv.z, bv.w};
      #pragma unroll
      for (int i = 0; i < 4; ++i)
        #pragma unroll
        for (int j = 0; j < 4; ++j)
          acc[i][j] = fmaf(ar[i], br[j], acc[i][j]);
    }
    __syncthreads();
  }

  const float4 bb = *(const float4*)(bias + col0 + tx * 4);
  #pragma unroll
  for (int i = 0; i < 4; ++i) {
    const int r = row0 + ty * 4 + i;
    if (r < M) {
      float4 o;
      o.x = acc[i][0] + bb.x; o.y = acc[i][1] + bb.y;
      o.z = acc[i][2] + bb.z; o.w = acc[i][3] + bb.w;
      *(float4*)(C + (size_t)r * N + col0 + tx * 4) = o;
    }
  }
}

// ---------------- cls attention: 1 query over all 1569 keys ----------------
// q = XQ row 0; keys = XK rows 0..1568; values = XV rows 0..1568.
// Writes FULL9[b][0][h*192 + d].
__global__ __launch_bounds__(256) void cls_attn_kernel(
    const float* __restrict__ XQ, const float* __restrict__ XK,
    const float* __restrict__ XV, float* __restrict__ FULL9, int b0) {
  const int h  = blockIdx.x % H_;
  const int bl = blockIdx.x / H_;
  const int b  = b0 + bl;
  __shared__ float qs[D3];
  __shared__ float sc[SEQ];
  __shared__ float red[4];
  const int tid = threadIdx.x;

  const float* Qr = XQ + (size_t)bl * SEQ * NCOL + h * D3;
  if (tid < 48) ((float4*)qs)[tid] = ((const float4*)Qr)[tid];
  __syncthreads();

  float lmax = -1e30f;
  for (int t = tid; t < SEQ; t += 256) {
    const float* kr = XK + ((size_t)bl * SEQ + t) * NCOL + h * D3;
    float acc = 0.f;
    #pragma unroll 4
    for (int d = 0; d < D3; d += 4) {
      const float4 k4 = *(const float4*)(kr + d);
      acc = fmaf(qs[d], k4.x, acc);
      acc = fmaf(qs[d + 1], k4.y, acc);
      acc = fmaf(qs[d + 2], k4.z, acc);
      acc = fmaf(qs[d + 3], k4.w, acc);
    }
    acc *= RSCALE;
    sc[t] = acc;
    lmax = fmaxf(lmax, acc);
  }
  const float m = block_max256(lmax, red);
  float lsum = 0.f;
  for (int t = tid; t < SEQ; t += 256) {
    const float e = expf(sc[t] - m);
    sc[t] = e;
    lsum += e;
  }
  const float D = block_sum256(lsum, red);
  __syncthreads();
  if (tid < D3) {
    float acc = 0.f;
    const float* vbase = XV + (size_t)bl * SEQ * NCOL + h * D3 + tid;
    for (int t = 0; t < SEQ; ++t) acc = fmaf(sc[t], vbase[(size_t)t * NCOL], acc);
    FULL9[((size_t)b * 9 + 0) * NCOL + h * D3 + tid] = acc / D;
  }
}

// ---------------- temporal attention per (b, h, patch) ----------------
// q from XQ, k from XV (km!), v from XK (vm!), rows f*196 + pi + 2.
// t1u = sum_g (sum_f softmax_g(q_f.k_g/96)) * v_g ; write merged T1U[b][pi][h*192+d].
__global__ __launch_bounds__(64) void temporal_kernel(
    const float* __restrict__ XQ, const float* __restrict__ XK,
    const float* __restrict__ XV, float* __restrict__ T1U, int b0) {
  const int id = blockIdx.x;
  const int pi = id % P1;
  const int h  = (id / P1) % H_;
  const int bl = id / (P1 * H_);
  const int b  = b0 + bl;
  __shared__ float qs[8][196], ks[8][196], vs[8][196];
  __shared__ float wg[8];
  const int tid = threadIdx.x;  // 64

  #pragma unroll
  for (int i = 0; i < 6; ++i) {
    const int idx = tid + 64 * i;      // 0..383
    const int f = idx / 48, d4 = idx % 48;
    const size_t base = ((size_t)bl * SEQ + (size_t)f * NP + pi + 2) * NCOL + h * D3 + d4 * 4;
    *(float4*)&qs[f][d4 * 4] = *(const float4*)(XQ + base);
    *(float4*)&ks[f][d4 * 4] = *(const float4*)(XV + base);  // keys from Wv proj
    *(float4*)&vs[f][d4 * 4] = *(const float4*)(XK + base);  // values from Wk proj
  }
  __syncthreads();

  const int f = tid >> 3, g = tid & 7;
  float s = 0.f;
  for (int d = 0; d < D3; ++d) s = fmaf(qs[f][d], ks[g][d], s);
  s *= RSCALE;

  float m = s;
  #pragma unroll
  for (int o = 1; o < 8; o <<= 1) m = fmaxf(m, __shfl_xor(m, o, 64));
  const float e = expf(s - m);
  float sum = e;
  #pragma unroll
  for (int o = 1; o < 8; o <<= 1) sum += __shfl_xor(sum, o, 64);
  float a = e / sum;
  // column sums over f: xor across the f bits (8,16,32)
  #pragma unroll
  for (int o = 8; o < 64; o <<= 1) a += __shfl_xor(a, o, 64);
  if (tid < 8) wg[tid] = a;
  __syncthreads();

  #pragma unroll
  for (int i = 0; i < 3; ++i) {
    const int d = tid + 64 * i;
    float o = 0.f;
    #pragma unroll
    for (int gg = 0; gg < 8; ++gg) o = fmaf(wg[gg], vs[gg][d], o);
    T1U[((size_t)b * P1 + pi) * NCOL + h * D3 + d] = o;
  }
}

// ---------------- stage-2, xi = 0: 195(+dup) queries over 195(+dup key 0) keys --------
// out = sum_rq m_rq * softmax-output; key 0 counted twice in denom & numerator.
__global__ __launch_bounds__(256) void stage2_xi0_kernel(
    const float* __restrict__ Q2U, const float* __restrict__ K2U,
    const float* __restrict__ V2U, float* __restrict__ FULL9) {
  const int h = blockIdx.x % H_;
  const int b = blockIdx.x / H_;
  __shared__ float qs[D3];
  __shared__ float gacc[P1];
  __shared__ float red[4];
  const int tid = threadIdx.x;
  if (tid < P1) gacc[tid] = 0.f;

  for (int rq = 0; rq < P1; ++rq) {
    __syncthreads();
    if (tid < 48)
      ((float4*)qs)[tid] =
          *((const float4*)(Q2U + ((size_t)(b * P1 + rq)) * NCOL + h * D3) + tid);
    __syncthreads();
    float dot = -1e30f;
    if (tid < P1) {
      const float* kr = K2U + ((size_t)(b * P1 + tid)) * NCOL + h * D3;
      float acc = 0.f;
      #pragma unroll 4
      for (int d = 0; d < D3; d += 4) {
        const float4 k4 = *(const float4*)(kr + d);
        acc = fmaf(qs[d], k4.x, acc);
        acc = fmaf(qs[d + 1], k4.y, acc);
        acc = fmaf(qs[d + 2], k4.z, acc);
        acc = fmaf(qs[d + 3], k4.w, acc);
      }
      dot = acc * RSCALE;
    }
    const float m = block_max256(dot, red);
    float f = 0.f;
    if (tid < P1) f = expf(dot - m) * ((tid == 0) ? 2.f : 1.f);
    const float D = block_sum256(f, red);
    if (tid < P1) gacc[tid] += ((rq == 0) ? 2.f : 1.f) * f / D;
  }
  __syncthreads();
  if (tid < D3) {
    float acc = 0.f;
    const float* vbase = V2U + (size_t)b * P1 * NCOL + h * D3 + tid;
    for (int r = 0; r < P1; ++r) acc = fmaf(gacc[r], vbase[(size_t)r * NCOL], acc);
    FULL9[((size_t)b * 9 + 1) * NCOL + h * D3 + tid] = acc;
  }
}

// ---------------- stage-2, xi = 1..7: 195(+dup row xi) queries over 8 keys ----------
__global__ __launch_bounds__(256) void stage2_xi_kernel(
    const float* __restrict__ Q2U, const float* __restrict__ K2U,
    const float* __restrict__ V2U, float* __restrict__ FULL9) {
  const int xi = 1 + blockIdx.x % 7;
  const int h  = (blockIdx.x / 7) % H_;
  const int b  = blockIdx.x / (7 * H_);
  __shared__ float Ks[8][196], Vs[8][196], Qs[32][196];
  __shared__ float P[32][8];
  const int tid = threadIdx.x;

  for (int idx = tid; idx < 384; idx += 256) {
    const int k = idx / 48, d4 = idx % 48;
    const size_t base = ((size_t)(b * P1 + xi + k)) * NCOL + h * D3 + d4 * 4;
    *(float4*)&Ks[k][d4 * 4] = *(const float4*)(K2U + base);
    *(float4*)&Vs[k][d4 * 4] = *(const float4*)(V2U + base);
  }

  float acc = 0.f;  // for d = tid (tid < 192)
  for (int c = 0; c < 7; ++c) {
    __syncthreads();
    for (int idx = tid; idx < 32 * 48; idx += 256) {
      const int qr = idx / 48, d4 = idx % 48;
      const int rq = c * 32 + qr;
      float4 v = make_float4(0.f, 0.f, 0.f, 0.f);
      if (rq < P1)
        v = *(const float4*)(Q2U + ((size_t)(b * P1 + rq)) * NCOL + h * D3 + d4 * 4);
      *(float4*)&Qs[qr][d4 * 4] = v;
    }
    __syncthreads();
    const int grp = tid >> 3, k = tid & 7;
    float dot = 0.f;
    for (int d = 0; d < D3; ++d) dot = fmaf(Qs[grp][d], Ks[k][d], dot);
    dot *= RSCALE;
    float m = dot;
    #pragma unroll
    for (int o = 1; o < 8; o <<= 1) m = fmaxf(m, __shfl_xor(m, o, 64));
    const float e = expf(dot - m);
    float s = e;
    #pragma unroll
    for (int o = 1; o < 8; o <<= 1) s += __shfl_xor(s, o, 64);
    P[grp][k] = e / s;
    __syncthreads();
    if (tid < D3) {
      #pragma unroll 4
      for (int g2 = 0; g2 < 32; ++g2) {
        const int rq2 = c * 32 + g2;
        if (rq2 < P1) {
          const float mult = (rq2 == xi) ? 2.f : 1.f;
          float o = 0.f;
          #pragma unroll
          for (int kk = 0; kk < 8; ++kk) o = fmaf(P[g2][kk], Vs[kk][tid], o);
          acc = fmaf(mult, o, acc);
        }
      }
    }
  }
  if (tid < D3) FULL9[((size_t)b * 9 + 1 + xi) * NCOL + h * D3 + tid] = acc;
}

// ---------------- broadcast OUT9 -> full output ----------------
__global__ __launch_bounds__(256) void bcast_kernel(
    const float* __restrict__ OUT9, float* __restrict__ out) {
  const int idx = blockIdx.x * 256 + threadIdx.x;  // over float4s
  const int total = B_ * SEQ * (DIMX / 4);
  if (idx >= total) return;
  const int d4 = idx % (DIMX / 4);
  const int bs = idx / (DIMX / 4);
  const int s = bs % SEQ;
  const int b = bs / SEQ;
  const int row = (s == 0) ? 0 : 1 + ((s - 1) & 7);
  ((float4*)out)[idx] = ((const float4*)OUT9)[(size_t)(b * 9 + row) * (DIMX / 4) + d4];
}

// ---------------- launch ----------------
extern "C" void kernel_launch(void* const* d_in, const int* in_sizes, int n_in,
                              void* d_out, int out_size, void* d_ws, size_t ws_size,
                              hipStream_t stream) {
  const float* x  = (const float*)d_in[0];
  const float* Wq = (const float*)d_in[1];
  const float* bq = (const float*)d_in[2];
  const float* Wk = (const float*)d_in[3];
  const float* bk = (const float*)d_in[4];
  const float* Wv = (const float*)d_in[5];
  const float* bv = (const float*)d_in[6];
  const float* Wt = (const float*)d_in[7];
  const float* bt = (const float*)d_in[8];
  const float* Wf = (const float*)d_in[9];
  const float* bf = (const float*)d_in[10];
  float* out = (float*)d_out;
  (void)in_sizes; (void)n_in; (void)out_size;

  char* ws = (char*)d_ws;
  size_t off = 0;
  auto alloc = [&](size_t elems) {
    float* p = (float*)(ws + off);
    off += elems * sizeof(float);
    return p;
  };
  float* T1U   = alloc((size_t)B_ * P1 * NCOL);
  float* TIU   = alloc((size_t)B_ * P1 * DIMX);
  float* Q2U   = alloc((size_t)B_ * P1 * NCOL);
  float* V2U   = alloc((size_t)B_ * P1 * NCOL);
  float* K2U   = alloc((size_t)B_ * P1 * NCOL);
  float* FULL9 = alloc((size_t)B_ * 9 * NCOL);
  float* OUT9  = alloc((size_t)B_ * 9 * DIMX);

  const size_t remain = (ws_size > off) ? (ws_size - off) : 0;
  int Bc = 8;
  while (Bc > 1 && (size_t)3 * Bc * SEQ * NCOL * sizeof(float) > remain) Bc >>= 1;
  float* XQ = alloc((size_t)Bc * SEQ * NCOL);
  float* XK = alloc((size_t)Bc * SEQ * NCOL);
  float* XV = alloc((size_t)Bc * SEQ * NCOL);

  // ---- stage 1: projections + cls attention + temporal attention (chunked over batch)
  for (int b0 = 0; b0 < B_; b0 += Bc) {
    const int Mrows = Bc * SEQ;
    const float* Ach = x + (size_t)b0 * SEQ * DIMX;
    dim3 g1((Mrows + 63) / 64, NCOL / 64);
    gemm_bias_kernel<<<g1, 256, 0, stream>>>(Ach, Wq, bq, XQ, Mrows, NCOL, DIMX);
    gemm_bias_kernel<<<g1, 256, 0, stream>>>(Ach, Wk, bk, XK, Mrows, NCOL, DIMX);
    gemm_bias_kernel<<<g1, 256, 0, stream>>>(Ach, Wv, bv, XV, Mrows, NCOL, DIMX);
    cls_attn_kernel<<<dim3(Bc * H_), 256, 0, stream>>>(XQ, XK, XV, FULL9, b0);
    temporal_kernel<<<dim3(Bc * P1 * H_), 64, 0, stream>>>(XQ, XK, XV, T1U, b0);
  }

  // ---- stage 2: ti = merge(t1u) @ Wt + bt  (only 195 unique rows per batch)
  {
    dim3 g((B_ * P1 + 63) / 64, DIMX / 64);
    gemm_bias_kernel<<<g, 256, 0, stream>>>(T1U, Wt, bt, TIU, B_ * P1, DIMX, NCOL);
  }
  // ---- q2 = ti@Wq, v2 = ti@Wk, k2 = ti@Wv
  {
    dim3 g((B_ * P1 + 63) / 64, NCOL / 64);
    gemm_bias_kernel<<<g, 256, 0, stream>>>(TIU, Wq, bq, Q2U, B_ * P1, NCOL, DIMX);
    gemm_bias_kernel<<<g, 256, 0, stream>>>(TIU, Wk, bk, V2U, B_ * P1, NCOL, DIMX);
    gemm_bias_kernel<<<g, 256, 0, stream>>>(TIU, Wv, bv, K2U, B_ * P1, NCOL, DIMX);
  }

  // ---- stage-2 attentions -> FULL9 rows 1..8 (cls kernel already wrote row 0)
  stage2_xi0_kernel<<<dim3(B_ * H_), 256, 0, stream>>>(Q2U, K2U, V2U, FULL9);
  stage2_xi_kernel<<<dim3(B_ * H_ * 7), 256, 0, stream>>>(Q2U, K2U, V2U, FULL9);

  // ---- final projection on the 9 unique rows per batch
  {
    dim3 g((B_ * 9 + 63) / 64, DIMX / 64);
    gemm_bias_kernel<<<g, 256, 0, stream>>>(FULL9, Wf, bf, OUT9, B_ * 9, DIMX, NCOL);
  }

  // ---- broadcast to the full (B, 1569, 768) output
  {
    const int total4 = B_ * SEQ * (DIMX / 4);
    bcast_kernel<<<dim3((total4 + 255) / 256), 256, 0, stream>>>(OUT9, out);
  }
}

// Round 2
// 3772.928 us; speedup vs baseline: 1.1140x; 1.1140x over previous
//
#include <hip/hip_runtime.h>
#include <math.h>

// Problem constants
#define B_    8
#define SEQ   1569      // 1 + 196*8
#define DIMX  768
#define H_    12
#define D3    192       // head dim (3*DH)
#define F_    8
#define NP    196
#define P1    195       // patches kept per frame (p=1..195)
#define NCOL  2304      // 3*DIM
#define RSCALE (1.0f/96.0f)

// ---------------- block reduction helpers (blockDim == 256) ----------------
__device__ __forceinline__ float block_max256(float v, float* red) {
  #pragma unroll
  for (int o = 32; o > 0; o >>= 1) v = fmaxf(v, __shfl_xor(v, o, 64));
  __syncthreads();
  if ((threadIdx.x & 63) == 0) red[threadIdx.x >> 6] = v;
  __syncthreads();
  return fmaxf(fmaxf(red[0], red[1]), fmaxf(red[2], red[3]));
}

__device__ __forceinline__ float block_sum256(float v, float* red) {
  #pragma unroll
  for (int o = 32; o > 0; o >>= 1) v += __shfl_xor(v, o, 64);
  __syncthreads();
  if ((threadIdx.x & 63) == 0) red[threadIdx.x >> 6] = v;
  __syncthreads();
  return red[0] + red[1] + red[2] + red[3];
}

// ---------------- fp32 GEMM, 128x128 tile: C = A@W + bias ----------------
// A: M x K row-major, W: K x N row-major, bias: N, C: M x N.
// Requires K % 16 == 0, N % 128 == 0. M arbitrary.
// 256 threads; each computes an 8x8 (2x2 blocks of 4x4) sub-tile.
// LDS rows padded to 132 floats: staging scalar writes land 2-way per bank (free).
__global__ __launch_bounds__(256) void gemm_bias_128(
    const float* __restrict__ A, const float* __restrict__ W,
    const float* __restrict__ bias, float* __restrict__ C,
    int M, int N, int K) {
  __shared__ float As[16][132];   // As[k][m]
  __shared__ float Bs[16][132];   // Bs[k][n]
  const int tid  = threadIdx.x;
  const int row0 = blockIdx.x * 128;
  const int col0 = blockIdx.y * 128;
  const int tx = tid & 15, ty = tid >> 4;

  const int am = tid >> 2;           // 0..63
  const int ak = (tid & 3) * 4;      // 0,4,8,12
  const int bk = tid >> 5;           // 0..7
  const int bc = (tid & 31) * 4;     // 0..124

  float acc[2][2][4][4] = {};

  for (int k0 = 0; k0 < K; k0 += 16) {
    #pragma unroll
    for (int half = 0; half < 2; ++half) {
      const int r = row0 + am + half * 64;
      float4 a4 = make_float4(0.f, 0.f, 0.f, 0.f);
      if (r < M) a4 = *(const float4*)(A + (size_t)r * K + k0 + ak);
      As[ak + 0][am + half * 64] = a4.x;
      As[ak + 1][am + half * 64] = a4.y;
      As[ak + 2][am + half * 64] = a4.z;
      As[ak + 3][am + half * 64] = a4.w;
    }
    #pragma unroll
    for (int half = 0; half < 2; ++half) {
      const int kr = k0 + bk + half * 8;
      *(float4*)&Bs[bk + half * 8][bc] =
          *(const float4*)(W + (size_t)kr * N + col0 + bc);
    }
    __syncthreads();

    #pragma unroll
    for (int kk = 0; kk < 16; ++kk) {
      float ar[2][4], br[2][4];
      *(float4*)ar[0] = *(const float4*)&As[kk][ty * 4];
      *(float4*)ar[1] = *(const float4*)&As[kk][ty * 4 + 64];
      *(float4*)br[0] = *(const float4*)&Bs[kk][tx * 4];
      *(float4*)br[1] = *(const float4*)&Bs[kk][tx * 4 + 64];
      #pragma unroll
      for (int ih = 0; ih < 2; ++ih)
        #pragma unroll
        for (int i = 0; i < 4; ++i)
          #pragma unroll
          for (int jh = 0; jh < 2; ++jh)
            #pragma unroll
            for (int j = 0; j < 4; ++j)
              acc[ih][jh][i][j] = fmaf(ar[ih][i], br[jh][j], acc[ih][jh][i][j]);
    }
    __syncthreads();
  }

  float4 bb[2];
  #pragma unroll
  for (int jh = 0; jh < 2; ++jh)
    bb[jh] = *(const float4*)(bias + col0 + jh * 64 + tx * 4);
  #pragma unroll
  for (int ih = 0; ih < 2; ++ih)
    #pragma unroll
    for (int i = 0; i < 4; ++i) {
      const int r = row0 + ih * 64 + ty * 4 + i;
      if (r < M) {
        #pragma unroll
        for (int jh = 0; jh < 2; ++jh) {
          float4 o;
          o.x = acc[ih][jh][i][0] + bb[jh].x;
          o.y = acc[ih][jh][i][1] + bb[jh].y;
          o.z = acc[ih][jh][i][2] + bb[jh].z;
          o.w = acc[ih][jh][i][3] + bb[jh].w;
          *(float4*)(C + (size_t)r * N + col0 + jh * 64 + tx * 4) = o;
        }
      }
    }
}

// ---------------- cls attention: 1 query over all 1569 keys ----------------
__global__ __launch_bounds__(256) void cls_attn_kernel(
    const float* __restrict__ XQ, const float* __restrict__ XK,
    const float* __restrict__ XV, float* __restrict__ FULL9, int b0) {
  const int h  = blockIdx.x % H_;
  const int bl = blockIdx.x / H_;
  const int b  = b0 + bl;
  __shared__ float qs[D3];
  __shared__ float sc[SEQ];
  __shared__ float red[4];
  const int tid = threadIdx.x;

  const float* Qr = XQ + (size_t)bl * SEQ * NCOL + h * D3;
  if (tid < 48) ((float4*)qs)[tid] = ((const float4*)Qr)[tid];
  __syncthreads();

  float lmax = -1e30f;
  for (int t = tid; t < SEQ; t += 256) {
    const float* kr = XK + ((size_t)bl * SEQ + t) * NCOL + h * D3;
    float acc = 0.f;
    #pragma unroll 4
    for (int d = 0; d < D3; d += 4) {
      const float4 k4 = *(const float4*)(kr + d);
      acc = fmaf(qs[d], k4.x, acc);
      acc = fmaf(qs[d + 1], k4.y, acc);
      acc = fmaf(qs[d + 2], k4.z, acc);
      acc = fmaf(qs[d + 3], k4.w, acc);
    }
    acc *= RSCALE;
    sc[t] = acc;
    lmax = fmaxf(lmax, acc);
  }
  const float m = block_max256(lmax, red);
  float lsum = 0.f;
  for (int t = tid; t < SEQ; t += 256) {
    const float e = expf(sc[t] - m);
    sc[t] = e;
    lsum += e;
  }
  const float D = block_sum256(lsum, red);
  __syncthreads();
  if (tid < D3) {
    float acc = 0.f;
    const float* vbase = XV + (size_t)bl * SEQ * NCOL + h * D3 + tid;
    for (int t = 0; t < SEQ; ++t) acc = fmaf(sc[t], vbase[(size_t)t * NCOL], acc);
    FULL9[((size_t)b * 9 + 0) * NCOL + h * D3 + tid] = acc / D;
  }
}

// ---------------- temporal attention per (b, h, patch) ----------------
__global__ __launch_bounds__(64) void temporal_kernel(
    const float* __restrict__ XQ, const float* __restrict__ XK,
    const float* __restrict__ XV, float* __restrict__ T1U, int b0) {
  const int id = blockIdx.x;
  const int pi = id % P1;
  const int h  = (id / P1) % H_;
  const int bl = id / (P1 * H_);
  const int b  = b0 + bl;
  __shared__ float qs[8][196], ks[8][196], vs[8][196];
  __shared__ float wg[8];
  const int tid = threadIdx.x;  // 64

  #pragma unroll
  for (int i = 0; i < 6; ++i) {
    const int idx = tid + 64 * i;      // 0..383
    const int f = idx / 48, d4 = idx % 48;
    const size_t base = ((size_t)bl * SEQ + (size_t)f * NP + pi + 2) * NCOL + h * D3 + d4 * 4;
    *(float4*)&qs[f][d4 * 4] = *(const float4*)(XQ + base);
    *(float4*)&ks[f][d4 * 4] = *(const float4*)(XV + base);  // keys from Wv proj
    *(float4*)&vs[f][d4 * 4] = *(const float4*)(XK + base);  // values from Wk proj
  }
  __syncthreads();

  const int f = tid >> 3, g = tid & 7;
  float s = 0.f;
  for (int d = 0; d < D3; ++d) s = fmaf(qs[f][d], ks[g][d], s);
  s *= RSCALE;

  float m = s;
  #pragma unroll
  for (int o = 1; o < 8; o <<= 1) m = fmaxf(m, __shfl_xor(m, o, 64));
  const float e = expf(s - m);
  float sum = e;
  #pragma unroll
  for (int o = 1; o < 8; o <<= 1) sum += __shfl_xor(sum, o, 64);
  float a = e / sum;
  #pragma unroll
  for (int o = 8; o < 64; o <<= 1) a += __shfl_xor(a, o, 64);
  if (tid < 8) wg[tid] = a;
  __syncthreads();

  #pragma unroll
  for (int i = 0; i < 3; ++i) {
    const int d = tid + 64 * i;
    float o = 0.f;
    #pragma unroll
    for (int gg = 0; gg < 8; ++gg) o = fmaf(wg[gg], vs[gg][d], o);
    T1U[((size_t)b * P1 + pi) * NCOL + h * D3 + d] = o;
  }
}

// ---------------- stage-2, xi = 0 (parallel): scores per (b,h,query) ----------
// One block per (b,h,rq). Thread k computes dot(q_rq, k_k); block softmax;
// writes weight (with query/key-0 multiplicities) to Wmat[bh][k][rq].
__global__ __launch_bounds__(256) void xi0_scores_kernel(
    const float* __restrict__ Q2U, const float* __restrict__ K2U,
    float* __restrict__ Wmat) {
  const int rq = blockIdx.x % P1;
  const int bh = blockIdx.x / P1;   // b*H + h
  const int h  = bh % H_, b = bh / H_;
  __shared__ float qs[D3];
  __shared__ float red[4];
  const int tid = threadIdx.x;

  if (tid < 48)
    ((float4*)qs)[tid] =
        *((const float4*)(Q2U + ((size_t)(b * P1 + rq)) * NCOL + h * D3) + tid);
  __syncthreads();

  float dot = -1e30f;
  if (tid < P1) {
    const float* kr = K2U + ((size_t)(b * P1 + tid)) * NCOL + h * D3;
    float acc = 0.f;
    #pragma unroll 4
    for (int d = 0; d < D3; d += 4) {
      const float4 k4 = *(const float4*)(kr + d);
      acc = fmaf(qs[d], k4.x, acc);
      acc = fmaf(qs[d + 1], k4.y, acc);
      acc = fmaf(qs[d + 2], k4.z, acc);
      acc = fmaf(qs[d + 3], k4.w, acc);
    }
    dot = acc * RSCALE;
  }
  const float m = block_max256(dot, red);
  float f = 0.f;
  if (tid < P1) f = expf(dot - m) * ((tid == 0) ? 2.f : 1.f);  // key 0 dup
  const float D = block_sum256(f, red);
  if (tid < P1)
    Wmat[((size_t)bh * P1 + tid) * P1 + rq] = ((rq == 0) ? 2.f : 1.f) * f / D;
}

// ---------------- stage-2, xi = 0: reduce weights, apply V ----------------
__global__ __launch_bounds__(256) void xi0_reduce_kernel(
    const float* __restrict__ Wmat, const float* __restrict__ V2U,
    float* __restrict__ FULL9) {
  const int bh = blockIdx.x;
  const int h = bh % H_, b = bh / H_;
  __shared__ float g[P1];
  const int tid = threadIdx.x;
  if (tid < P1) {
    const float* wr = Wmat + ((size_t)bh * P1 + tid) * P1;
    float s = 0.f;
    for (int r = 0; r < P1; ++r) s += wr[r];
    g[tid] = s;
  }
  __syncthreads();
  if (tid < D3) {
    float acc = 0.f;
    const float* vbase = V2U + (size_t)b * P1 * NCOL + h * D3 + tid;
    for (int k = 0; k < P1; ++k) acc = fmaf(g[k], vbase[(size_t)k * NCOL], acc);
    FULL9[((size_t)b * 9 + 1) * NCOL + h * D3 + tid] = acc;
  }
}

// ---------------- stage-2, xi = 1..7: 195(+dup row xi) queries over 8 keys ----------
__global__ __launch_bounds__(256) void stage2_xi_kernel(
    const float* __restrict__ Q2U, const float* __restrict__ K2U,
    const float* __restrict__ V2U, float* __restrict__ FULL9) {
  const int xi = 1 + blockIdx.x % 7;
  const int h  = (blockIdx.x / 7) % H_;
  const int b  = blockIdx.x / (7 * H_);
  __shared__ float Ks[8][196], Vs[8][196], Qs[32][196];
  __shared__ float P[32][8];
  const int tid = threadIdx.x;

  for (int idx = tid; idx < 384; idx += 256) {
    const int k = idx / 48, d4 = idx % 48;
    const size_t base = ((size_t)(b * P1 + xi + k)) * NCOL + h * D3 + d4 * 4;
    *(float4*)&Ks[k][d4 * 4] = *(const float4*)(K2U + base);
    *(float4*)&Vs[k][d4 * 4] = *(const float4*)(V2U + base);
  }

  float acc = 0.f;  // for d = tid (tid < 192)
  for (int c = 0; c < 7; ++c) {
    __syncthreads();
    for (int idx = tid; idx < 32 * 48; idx += 256) {
      const int qr = idx / 48, d4 = idx % 48;
      const int rq = c * 32 + qr;
      float4 v = make_float4(0.f, 0.f, 0.f, 0.f);
      if (rq < P1)
        v = *(const float4*)(Q2U + ((size_t)(b * P1 + rq)) * NCOL + h * D3 + d4 * 4);
      *(float4*)&Qs[qr][d4 * 4] = v;
    }
    __syncthreads();
    const int grp = tid >> 3, k = tid & 7;
    float dot = 0.f;
    for (int d = 0; d < D3; ++d) dot = fmaf(Qs[grp][d], Ks[k][d], dot);
    dot *= RSCALE;
    float m = dot;
    #pragma unroll
    for (int o = 1; o < 8; o <<= 1) m = fmaxf(m, __shfl_xor(m, o, 64));
    const float e = expf(dot - m);
    float s = e;
    #pragma unroll
    for (int o = 1; o < 8; o <<= 1) s += __shfl_xor(s, o, 64);
    P[grp][k] = e / s;
    __syncthreads();
    if (tid < D3) {
      #pragma unroll 4
      for (int g2 = 0; g2 < 32; ++g2) {
        const int rq2 = c * 32 + g2;
        if (rq2 < P1) {
          const float mult = (rq2 == xi) ? 2.f : 1.f;
          float o = 0.f;
          #pragma unroll
          for (int kk = 0; kk < 8; ++kk) o = fmaf(P[g2][kk], Vs[kk][tid], o);
          acc = fmaf(mult, o, acc);
        }
      }
    }
  }
  if (tid < D3) FULL9[((size_t)b * 9 + 1 + xi) * NCOL + h * D3 + tid] = acc;
}

// ---------------- broadcast OUT9 -> full output ----------------
__global__ __launch_bounds__(256) void bcast_kernel(
    const float* __restrict__ OUT9, float* __restrict__ out) {
  const int idx = blockIdx.x * 256 + threadIdx.x;  // over float4s
  const int total = B_ * SEQ * (DIMX / 4);
  if (idx >= total) return;
  const int d4 = idx % (DIMX / 4);
  const int bs = idx / (DIMX / 4);
  const int s = bs % SEQ;
  const int b = bs / SEQ;
  const int row = (s == 0) ? 0 : 1 + ((s - 1) & 7);
  ((float4*)out)[idx] = ((const float4*)OUT9)[(size_t)(b * 9 + row) * (DIMX / 4) + d4];
}

// ---------------- launch ----------------
extern "C" void kernel_launch(void* const* d_in, const int* in_sizes, int n_in,
                              void* d_out, int out_size, void* d_ws, size_t ws_size,
                              hipStream_t stream) {
  const float* x  = (const float*)d_in[0];
  const float* Wq = (const float*)d_in[1];
  const float* bq = (const float*)d_in[2];
  const float* Wk = (const float*)d_in[3];
  const float* bk = (const float*)d_in[4];
  const float* Wv = (const float*)d_in[5];
  const float* bv = (const float*)d_in[6];
  const float* Wt = (const float*)d_in[7];
  const float* bt = (const float*)d_in[8];
  const float* Wf = (const float*)d_in[9];
  const float* bf = (const float*)d_in[10];
  float* out = (float*)d_out;
  (void)in_sizes; (void)n_in; (void)out_size;

  char* ws = (char*)d_ws;
  size_t off = 0;
  auto alloc = [&](size_t elems) {
    float* p = (float*)(ws + off);
    off += elems * sizeof(float);
    return p;
  };
  float* T1U   = alloc((size_t)B_ * P1 * NCOL);
  float* TIU   = alloc((size_t)B_ * P1 * DIMX);
  float* Q2U   = alloc((size_t)B_ * P1 * NCOL);
  float* V2U   = alloc((size_t)B_ * P1 * NCOL);
  float* K2U   = alloc((size_t)B_ * P1 * NCOL);
  float* FULL9 = alloc((size_t)B_ * 9 * NCOL);
  float* OUT9  = alloc((size_t)B_ * 9 * DIMX);
  float* Wmat  = alloc((size_t)B_ * H_ * P1 * P1);

  const size_t remain = (ws_size > off) ? (ws_size - off) : 0;
  int Bc = 8;
  while (Bc > 1 && (size_t)3 * Bc * SEQ * NCOL * sizeof(float) > remain) Bc >>= 1;
  float* XQ = alloc((size_t)Bc * SEQ * NCOL);
  float* XK = alloc((size_t)Bc * SEQ * NCOL);
  float* XV = alloc((size_t)Bc * SEQ * NCOL);

  // ---- stage 1: projections + cls attention + temporal attention (chunked)
  for (int b0 = 0; b0 < B_; b0 += Bc) {
    const int Mrows = Bc * SEQ;
    const float* Ach = x + (size_t)b0 * SEQ * DIMX;
    dim3 g1((Mrows + 127) / 128, NCOL / 128);
    gemm_bias_128<<<g1, 256, 0, stream>>>(Ach, Wq, bq, XQ, Mrows, NCOL, DIMX);
    gemm_bias_128<<<g1, 256, 0, stream>>>(Ach, Wk, bk, XK, Mrows, NCOL, DIMX);
    gemm_bias_128<<<g1, 256, 0, stream>>>(Ach, Wv, bv, XV, Mrows, NCOL, DIMX);
    cls_attn_kernel<<<dim3(Bc * H_), 256, 0, stream>>>(XQ, XK, XV, FULL9, b0);
    temporal_kernel<<<dim3(Bc * P1 * H_), 64, 0, stream>>>(XQ, XK, XV, T1U, b0);
  }

  // ---- stage 2: ti = merge(t1u) @ Wt + bt  (195 unique rows per batch)
  {
    dim3 g((B_ * P1 + 127) / 128, DIMX / 128);
    gemm_bias_128<<<g, 256, 0, stream>>>(T1U, Wt, bt, TIU, B_ * P1, DIMX, NCOL);
  }
  // ---- q2 = ti@Wq, v2 = ti@Wk, k2 = ti@Wv
  {
    dim3 g((B_ * P1 + 127) / 128, NCOL / 128);
    gemm_bias_128<<<g, 256, 0, stream>>>(TIU, Wq, bq, Q2U, B_ * P1, NCOL, DIMX);
    gemm_bias_128<<<g, 256, 0, stream>>>(TIU, Wk, bk, V2U, B_ * P1, NCOL, DIMX);
    gemm_bias_128<<<g, 256, 0, stream>>>(TIU, Wv, bv, K2U, B_ * P1, NCOL, DIMX);
  }

  // ---- stage-2 attentions -> FULL9 rows 1..8
  xi0_scores_kernel<<<dim3(B_ * H_ * P1), 256, 0, stream>>>(Q2U, K2U, Wmat);
  xi0_reduce_kernel<<<dim3(B_ * H_), 256, 0, stream>>>(Wmat, V2U, FULL9);
  stage2_xi_kernel<<<dim3(B_ * H_ * 7), 256, 0, stream>>>(Q2U, K2U, V2U, FULL9);

  // ---- final projection on the 9 unique rows per batch
  {
    dim3 g((B_ * 9 + 127) / 128, DIMX / 128);
    gemm_bias_128<<<g, 256, 0, stream>>>(FULL9, Wf, bf, OUT9, B_ * 9, DIMX, NCOL);
  }

  // ---- broadcast to the full (B, 1569, 768) output
  {
    const int total4 = B_ * SEQ * (DIMX / 4);
    bcast_kernel<<<dim3((total4 + 255) / 256), 256, 0, stream>>>(OUT9, out);
  }
}

// Round 3
// 1774.403 us; speedup vs baseline: 2.3686x; 2.1263x over previous
//
#include <hip/hip_runtime.h>
#include <math.h>

// Problem constants
#define B_    8
#define SEQ   1569      // 1 + 196*8
#define DIMX  768
#define H_    12
#define D3    192       // head dim slice (3*DH)
#define F_    8
#define NP    196
#define P1    195       // patches kept per frame
#define NCOL  2304      // 3*DIM
#define RSCALE (1.0f/96.0f)

typedef __bf16 bf16_t;
typedef bf16_t bf16x8 __attribute__((ext_vector_type(8)));
typedef float  f32x4  __attribute__((ext_vector_type(4)));

// ---------------- block reduction helpers (blockDim == 256) ----------------
__device__ __forceinline__ float block_max256(float v, float* red) {
  #pragma unroll
  for (int o = 32; o > 0; o >>= 1) v = fmaxf(v, __shfl_xor(v, o, 64));
  __syncthreads();
  if ((threadIdx.x & 63) == 0) red[threadIdx.x >> 6] = v;
  __syncthreads();
  return fmaxf(fmaxf(red[0], red[1]), fmaxf(red[2], red[3]));
}

__device__ __forceinline__ float block_sum256(float v, float* red) {
  #pragma unroll
  for (int o = 32; o > 0; o >>= 1) v += __shfl_xor(v, o, 64);
  __syncthreads();
  if ((threadIdx.x & 63) == 0) red[threadIdx.x >> 6] = v;
  __syncthreads();
  return red[0] + red[1] + red[2] + red[3];
}

// ---------------- cast fp32 -> bf16 (vector of 4) ----------------
__global__ __launch_bounds__(256) void cast_f32_bf16(
    const float* __restrict__ in, bf16_t* __restrict__ out, int n4) {
  const int i = blockIdx.x * 256 + threadIdx.x;
  if (i >= n4) return;
  const float4 v = ((const float4*)in)[i];
  bf16_t o4[4] = {(bf16_t)v.x, (bf16_t)v.y, (bf16_t)v.z, (bf16_t)v.w};
  ((uint2*)out)[i] = *(uint2*)o4;
}

// ---------------- transpose + cast: W (K x N fp32) -> WT (N x K bf16) -------
__global__ __launch_bounds__(256) void transpose_cast(
    const float* __restrict__ W, bf16_t* __restrict__ WT, int Kd, int Nd) {
  __shared__ float t[32][33];
  const int bn = blockIdx.x * 32;
  const int bk = blockIdx.y * 32;
  const int tx = threadIdx.x & 31, ty = threadIdx.x >> 5;  // 32 x 8
  #pragma unroll
  for (int i = 0; i < 32; i += 8)
    t[ty + i][tx] = W[(size_t)(bk + ty + i) * Nd + bn + tx];
  __syncthreads();
  #pragma unroll
  for (int i = 0; i < 32; i += 8)
    WT[(size_t)(bn + ty + i) * Kd + bk + tx] = (bf16_t)t[tx][ty + i];
}

// ---------------- bf16 MFMA GEMM: C = A @ BT^T + bias ----------------
// A: M x K bf16 row-major. BT: N x K bf16 row-major (i.e. W transposed).
// bias: N fp32. C: M x N fp32. K % 32 == 0, N % 128 == 0, M arbitrary.
// 256 threads (4 waves); each wave computes a 64x64 quadrant via 4x4 MFMA tiles.
__global__ __launch_bounds__(256) void gemm_mfma_bt(
    const bf16_t* __restrict__ A, const bf16_t* __restrict__ BT,
    const float* __restrict__ bias, float* __restrict__ C,
    int M, int N, int K) {
  __shared__ bf16_t As[128][32];
  __shared__ bf16_t Bs[128][32];
  const int tid  = threadIdx.x;
  const int row0 = blockIdx.x * 128;
  const int col0 = blockIdx.y * 128;
  const int wave = tid >> 6;
  const int lane = tid & 63;
  const int m0 = (wave & 1) * 64;
  const int n0 = (wave >> 1) * 64;

  f32x4 acc[4][4] = {};

  for (int k0 = 0; k0 < K; k0 += 32) {
    #pragma unroll
    for (int i = 0; i < 2; ++i) {
      const int chunk = tid * 2 + i;   // 0..511 -> 128 rows x 4 segs of 16B
      const int r = chunk >> 2;
      const int seg = chunk & 3;
      int ar = row0 + r; if (ar >= M) ar = M - 1;   // clamp (masked on store)
      *(uint4*)&As[r][seg * 8] =
          *(const uint4*)(A + (size_t)ar * K + k0 + seg * 8);
      *(uint4*)&Bs[r][seg * 8] =
          *(const uint4*)(BT + (size_t)(col0 + r) * K + k0 + seg * 8);
    }
    __syncthreads();

    const int fr = lane & 15, k8 = (lane >> 4) * 8;
    bf16x8 af[4], bfr[4];
    #pragma unroll
    for (int i = 0; i < 4; ++i) {
      af[i]  = *(const bf16x8*)&As[m0 + i * 16 + fr][k8];
      bfr[i] = *(const bf16x8*)&Bs[n0 + i * 16 + fr][k8];
    }
    #pragma unroll
    for (int i = 0; i < 4; ++i)
      #pragma unroll
      for (int j = 0; j < 4; ++j)
        acc[i][j] = __builtin_amdgcn_mfma_f32_16x16x32_bf16(
            af[i], bfr[j], acc[i][j], 0, 0, 0);
    __syncthreads();
  }

  // C/D layout: col = lane&15, row = (lane>>4)*4 + reg
  const int cc = lane & 15, cr4 = (lane >> 4) * 4;
  #pragma unroll
  for (int i = 0; i < 4; ++i) {
    #pragma unroll
    for (int j = 0; j < 4; ++j) {
      const int col = col0 + n0 + j * 16 + cc;
      const float bcol = bias[col];
      #pragma unroll
      for (int reg = 0; reg < 4; ++reg) {
        const int r = row0 + m0 + i * 16 + cr4 + reg;
        if (r < M) C[(size_t)r * N + col] = acc[i][j][reg] + bcol;
      }
    }
  }
}

// ---------------- cls attention: 1 query over all 1569 keys ----------------
__global__ __launch_bounds__(256) void cls_attn_kernel(
    const float* __restrict__ XQ, const float* __restrict__ XK,
    const float* __restrict__ XV, float* __restrict__ FULL9, int b0) {
  const int h  = blockIdx.x % H_;
  const int bl = blockIdx.x / H_;
  const int b  = b0 + bl;
  __shared__ float qs[D3];
  __shared__ float sc[SEQ];
  __shared__ float red[4];
  const int tid = threadIdx.x;

  const float* Qr = XQ + (size_t)bl * SEQ * NCOL + h * D3;
  if (tid < 48) ((float4*)qs)[tid] = ((const float4*)Qr)[tid];
  __syncthreads();

  float lmax = -1e30f;
  for (int t = tid; t < SEQ; t += 256) {
    const float* kr = XK + ((size_t)bl * SEQ + t) * NCOL + h * D3;
    float acc = 0.f;
    #pragma unroll 4
    for (int d = 0; d < D3; d += 4) {
      const float4 k4 = *(const float4*)(kr + d);
      acc = fmaf(qs[d], k4.x, acc);
      acc = fmaf(qs[d + 1], k4.y, acc);
      acc = fmaf(qs[d + 2], k4.z, acc);
      acc = fmaf(qs[d + 3], k4.w, acc);
    }
    acc *= RSCALE;
    sc[t] = acc;
    lmax = fmaxf(lmax, acc);
  }
  const float m = block_max256(lmax, red);
  float lsum = 0.f;
  for (int t = tid; t < SEQ; t += 256) {
    const float e = expf(sc[t] - m);
    sc[t] = e;
    lsum += e;
  }
  const float D = block_sum256(lsum, red);
  __syncthreads();
  if (tid < D3) {
    float acc = 0.f;
    const float* vbase = XV + (size_t)bl * SEQ * NCOL + h * D3 + tid;
    for (int t = 0; t < SEQ; ++t) acc = fmaf(sc[t], vbase[(size_t)t * NCOL], acc);
    FULL9[((size_t)b * 9 + 0) * NCOL + h * D3 + tid] = acc / D;
  }
}

// ---------------- temporal attention per (b, h, patch) ----------------
__global__ __launch_bounds__(64) void temporal_kernel(
    const float* __restrict__ XQ, const float* __restrict__ XK,
    const float* __restrict__ XV, float* __restrict__ T1U, int b0) {
  const int id = blockIdx.x;
  const int pi = id % P1;
  const int h  = (id / P1) % H_;
  const int bl = id / (P1 * H_);
  const int b  = b0 + bl;
  __shared__ float qs[8][196], ks[8][196], vs[8][196];
  __shared__ float wg[8];
  const int tid = threadIdx.x;  // 64

  #pragma unroll
  for (int i = 0; i < 6; ++i) {
    const int idx = tid + 64 * i;      // 0..383
    const int f = idx / 48, d4 = idx % 48;
    const size_t base = ((size_t)bl * SEQ + (size_t)f * NP + pi + 2) * NCOL + h * D3 + d4 * 4;
    *(float4*)&qs[f][d4 * 4] = *(const float4*)(XQ + base);
    *(float4*)&ks[f][d4 * 4] = *(const float4*)(XV + base);  // keys from Wv proj
    *(float4*)&vs[f][d4 * 4] = *(const float4*)(XK + base);  // values from Wk proj
  }
  __syncthreads();

  const int f = tid >> 3, g = tid & 7;
  float s = 0.f;
  for (int d = 0; d < D3; d += 4) {
    const float4 a4 = *(const float4*)&qs[f][d];
    const float4 b4 = *(const float4*)&ks[g][d];
    s = fmaf(a4.x, b4.x, s); s = fmaf(a4.y, b4.y, s);
    s = fmaf(a4.z, b4.z, s); s = fmaf(a4.w, b4.w, s);
  }
  s *= RSCALE;

  float m = s;
  #pragma unroll
  for (int o = 1; o < 8; o <<= 1) m = fmaxf(m, __shfl_xor(m, o, 64));
  const float e = expf(s - m);
  float sum = e;
  #pragma unroll
  for (int o = 1; o < 8; o <<= 1) sum += __shfl_xor(sum, o, 64);
  float a = e / sum;
  #pragma unroll
  for (int o = 8; o < 64; o <<= 1) a += __shfl_xor(a, o, 64);
  if (tid < 8) wg[tid] = a;
  __syncthreads();

  #pragma unroll
  for (int i = 0; i < 3; ++i) {
    const int d = tid + 64 * i;
    float o = 0.f;
    #pragma unroll
    for (int gg = 0; gg < 8; ++gg) o = fmaf(wg[gg], vs[gg][d], o);
    T1U[((size_t)b * P1 + pi) * NCOL + h * D3 + d] = o;
  }
}

// ---------------- stage-2, xi = 0: scores, 8 queries per block ----------
// grid (B*H, 25). Thread k computes dots vs 8 queries; softmax per query;
// writes Wmat[bh][rq][k] (coalesced in k).
__global__ __launch_bounds__(256) void xi0_scores_kernel(
    const float* __restrict__ Q2U, const float* __restrict__ K2U,
    float* __restrict__ Wmat) {
  const int bh = blockIdx.x;           // b*H + h
  const int h  = bh % H_, b = bh / H_;
  const int q0 = blockIdx.y * 8;
  __shared__ float qs[8][D3];
  __shared__ float red[4];
  const int tid = threadIdx.x;

  for (int idx = tid; idx < 8 * 48; idx += 256) {
    const int qi = idx / 48, d4 = idx % 48;
    int rq = q0 + qi; if (rq >= P1) rq = P1 - 1;
    *(float4*)&qs[qi][d4 * 4] =
        *(const float4*)(Q2U + ((size_t)(b * P1 + rq)) * NCOL + h * D3 + d4 * 4);
  }
  __syncthreads();

  float dot[8] = {0.f, 0.f, 0.f, 0.f, 0.f, 0.f, 0.f, 0.f};
  if (tid < P1) {
    const float* kr = K2U + ((size_t)(b * P1 + tid)) * NCOL + h * D3;
    for (int d = 0; d < D3; d += 4) {
      const float4 k4 = *(const float4*)(kr + d);
      #pragma unroll
      for (int qi = 0; qi < 8; ++qi) {
        const float4 q4 = *(const float4*)&qs[qi][d];  // LDS broadcast
        dot[qi] = fmaf(k4.x, q4.x, dot[qi]);
        dot[qi] = fmaf(k4.y, q4.y, dot[qi]);
        dot[qi] = fmaf(k4.z, q4.z, dot[qi]);
        dot[qi] = fmaf(k4.w, q4.w, dot[qi]);
      }
    }
  }
  #pragma unroll
  for (int qi = 0; qi < 8; ++qi) {
    const int rq = q0 + qi;
    const float v = (tid < P1) ? dot[qi] * RSCALE : -1e30f;
    const float m = block_max256(v, red);
    const float f = (tid < P1) ? expf(v - m) * ((tid == 0) ? 2.f : 1.f) : 0.f;
    const float D = block_sum256(f, red);
    if (tid < P1 && rq < P1)
      Wmat[((size_t)bh * P1 + rq) * P1 + tid] = ((rq == 0) ? 2.f : 1.f) * f / D;
  }
}

// ---------------- stage-2, xi = 0: reduce weights over queries, apply V ------
__global__ __launch_bounds__(256) void xi0_reduce_kernel(
    const float* __restrict__ Wmat, const float* __restrict__ V2U,
    float* __restrict__ FULL9) {
  const int bh = blockIdx.x;
  const int h = bh % H_, b = bh / H_;
  __shared__ float g[P1];
  const int tid = threadIdx.x;
  if (tid < P1) {
    float s = 0.f;
    for (int r = 0; r < P1; ++r) s += Wmat[((size_t)bh * P1 + r) * P1 + tid];
    g[tid] = s;
  }
  __syncthreads();
  if (tid < D3) {
    float acc = 0.f;
    const float* vbase = V2U + (size_t)b * P1 * NCOL + h * D3 + tid;
    for (int k = 0; k < P1; ++k) acc = fmaf(g[k], vbase[(size_t)k * NCOL], acc);
    FULL9[((size_t)b * 9 + 1) * NCOL + h * D3 + tid] = acc;
  }
}

// ---------------- stage-2, xi = 1..7: 195(+dup row xi) queries over 8 keys ----
__global__ __launch_bounds__(256) void stage2_xi_kernel(
    const float* __restrict__ Q2U, const float* __restrict__ K2U,
    const float* __restrict__ V2U, float* __restrict__ FULL9) {
  const int xi = 1 + blockIdx.x % 7;
  const int h  = (blockIdx.x / 7) % H_;
  const int b  = blockIdx.x / (7 * H_);
  __shared__ float Ks[8][196], Vs[8][196], Qs[32][196];
  __shared__ float P[32][8];
  const int tid = threadIdx.x;

  for (int idx = tid; idx < 384; idx += 256) {
    const int k = idx / 48, d4 = idx % 48;
    const size_t base = ((size_t)(b * P1 + xi + k)) * NCOL + h * D3 + d4 * 4;
    *(float4*)&Ks[k][d4 * 4] = *(const float4*)(K2U + base);
    *(float4*)&Vs[k][d4 * 4] = *(const float4*)(V2U + base);
  }

  float acc = 0.f;  // for d = tid (tid < 192)
  for (int c = 0; c < 7; ++c) {
    __syncthreads();
    for (int idx = tid; idx < 32 * 48; idx += 256) {
      const int qr = idx / 48, d4 = idx % 48;
      const int rq = c * 32 + qr;
      float4 v = make_float4(0.f, 0.f, 0.f, 0.f);
      if (rq < P1)
        v = *(const float4*)(Q2U + ((size_t)(b * P1 + rq)) * NCOL + h * D3 + d4 * 4);
      *(float4*)&Qs[qr][d4 * 4] = v;
    }
    __syncthreads();
    const int grp = tid >> 3, k = tid & 7;
    float dot = 0.f;
    for (int d = 0; d < D3; d += 4) {
      const float4 a4 = *(const float4*)&Qs[grp][d];
      const float4 b4 = *(const float4*)&Ks[k][d];
      dot = fmaf(a4.x, b4.x, dot); dot = fmaf(a4.y, b4.y, dot);
      dot = fmaf(a4.z, b4.z, dot); dot = fmaf(a4.w, b4.w, dot);
    }
    dot *= RSCALE;
    float m = dot;
    #pragma unroll
    for (int o = 1; o < 8; o <<= 1) m = fmaxf(m, __shfl_xor(m, o, 64));
    const float e = expf(dot - m);
    float s = e;
    #pragma unroll
    for (int o = 1; o < 8; o <<= 1) s += __shfl_xor(s, o, 64);
    P[grp][k] = e / s;
    __syncthreads();
    if (tid < D3) {
      #pragma unroll 4
      for (int g2 = 0; g2 < 32; ++g2) {
        const int rq2 = c * 32 + g2;
        if (rq2 < P1) {
          const float mult = (rq2 == xi) ? 2.f : 1.f;
          float o = 0.f;
          #pragma unroll
          for (int kk = 0; kk < 8; ++kk) o = fmaf(P[g2][kk], Vs[kk][tid], o);
          acc = fmaf(mult, o, acc);
        }
      }
    }
  }
  if (tid < D3) FULL9[((size_t)b * 9 + 1 + xi) * NCOL + h * D3 + tid] = acc;
}

// ---------------- broadcast OUT9 -> full output ----------------
__global__ __launch_bounds__(256) void bcast_kernel(
    const float* __restrict__ OUT9, float* __restrict__ out) {
  const int idx = blockIdx.x * 256 + threadIdx.x;  // over float4s
  const int total = B_ * SEQ * (DIMX / 4);
  if (idx >= total) return;
  const int d4 = idx % (DIMX / 4);
  const int bs = idx / (DIMX / 4);
  const int s = bs % SEQ;
  const int b = bs / SEQ;
  const int row = (s == 0) ? 0 : 1 + ((s - 1) & 7);
  ((float4*)out)[idx] = ((const float4*)OUT9)[(size_t)(b * 9 + row) * (DIMX / 4) + d4];
}

// ---------------- launch ----------------
extern "C" void kernel_launch(void* const* d_in, const int* in_sizes, int n_in,
                              void* d_out, int out_size, void* d_ws, size_t ws_size,
                              hipStream_t stream) {
  const float* x  = (const float*)d_in[0];
  const float* Wq = (const float*)d_in[1];
  const float* bq = (const float*)d_in[2];
  const float* Wk = (const float*)d_in[3];
  const float* bk = (const float*)d_in[4];
  const float* Wv = (const float*)d_in[5];
  const float* bv = (const float*)d_in[6];
  const float* Wt = (const float*)d_in[7];
  const float* bt = (const float*)d_in[8];
  const float* Wf = (const float*)d_in[9];
  const float* bf = (const float*)d_in[10];
  float* out = (float*)d_out;
  (void)in_sizes; (void)n_in; (void)out_size;

  char* ws = (char*)d_ws;
  size_t off = 0;
  auto alloc_f32 = [&](size_t elems) {
    size_t a = (off + 63) & ~(size_t)63;
    off = a + elems * sizeof(float);
    return (float*)(ws + a);
  };
  auto alloc_bf16 = [&](size_t elems) {
    size_t a = (off + 63) & ~(size_t)63;
    off = a + elems * sizeof(bf16_t);
    return (bf16_t*)(ws + a);
  };

  float*  T1U    = alloc_f32((size_t)B_ * P1 * NCOL);
  float*  TIU    = alloc_f32((size_t)B_ * P1 * DIMX);
  float*  Q2U    = alloc_f32((size_t)B_ * P1 * NCOL);
  float*  V2U    = alloc_f32((size_t)B_ * P1 * NCOL);
  float*  K2U    = alloc_f32((size_t)B_ * P1 * NCOL);
  float*  FULL9  = alloc_f32((size_t)B_ * 9 * NCOL);
  float*  OUT9   = alloc_f32((size_t)B_ * 9 * DIMX);
  float*  Wmat   = alloc_f32((size_t)B_ * H_ * P1 * P1);
  bf16_t* WqT    = alloc_bf16((size_t)NCOL * DIMX);
  bf16_t* WkT    = alloc_bf16((size_t)NCOL * DIMX);
  bf16_t* WvT    = alloc_bf16((size_t)NCOL * DIMX);
  bf16_t* WtT    = alloc_bf16((size_t)DIMX * NCOL);
  bf16_t* WfT    = alloc_bf16((size_t)DIMX * NCOL);
  bf16_t* T1Ub   = alloc_bf16((size_t)B_ * P1 * NCOL);
  bf16_t* TIUb   = alloc_bf16((size_t)B_ * P1 * DIMX);
  bf16_t* FULL9b = alloc_bf16((size_t)B_ * 9 * NCOL);

  // chunked stage-1 buffers
  const size_t remain = (ws_size > off) ? (ws_size - off) : 0;
  int Bc = 8;
  while (Bc > 1 &&
         (size_t)Bc * SEQ * (3 * NCOL * sizeof(float) + DIMX * sizeof(bf16_t)) + 256 > remain)
    Bc >>= 1;
  float*  XQ = alloc_f32((size_t)Bc * SEQ * NCOL);
  float*  XK = alloc_f32((size_t)Bc * SEQ * NCOL);
  float*  XV = alloc_f32((size_t)Bc * SEQ * NCOL);
  bf16_t* xb = alloc_bf16((size_t)Bc * SEQ * DIMX);

  // ---- weight transposes (bf16)
  transpose_cast<<<dim3(NCOL / 32, DIMX / 32), 256, 0, stream>>>(Wq, WqT, DIMX, NCOL);
  transpose_cast<<<dim3(NCOL / 32, DIMX / 32), 256, 0, stream>>>(Wk, WkT, DIMX, NCOL);
  transpose_cast<<<dim3(NCOL / 32, DIMX / 32), 256, 0, stream>>>(Wv, WvT, DIMX, NCOL);
  transpose_cast<<<dim3(DIMX / 32, NCOL / 32), 256, 0, stream>>>(Wt, WtT, NCOL, DIMX);
  transpose_cast<<<dim3(DIMX / 32, NCOL / 32), 256, 0, stream>>>(Wf, WfT, NCOL, DIMX);

  // ---- stage 1 (chunked over batch): cast x, bf16 GEMMs, cls + temporal attn
  for (int b0 = 0; b0 < B_; b0 += Bc) {
    const int Mrows = Bc * SEQ;
    const int n4 = Mrows * DIMX / 4;
    cast_f32_bf16<<<dim3((n4 + 255) / 256), 256, 0, stream>>>(
        x + (size_t)b0 * SEQ * DIMX, xb, n4);
    dim3 g1((Mrows + 127) / 128, NCOL / 128);
    gemm_mfma_bt<<<g1, 256, 0, stream>>>(xb, WqT, bq, XQ, Mrows, NCOL, DIMX);
    gemm_mfma_bt<<<g1, 256, 0, stream>>>(xb, WkT, bk, XK, Mrows, NCOL, DIMX);
    gemm_mfma_bt<<<g1, 256, 0, stream>>>(xb, WvT, bv, XV, Mrows, NCOL, DIMX);
    cls_attn_kernel<<<dim3(Bc * H_), 256, 0, stream>>>(XQ, XK, XV, FULL9, b0);
    temporal_kernel<<<dim3(Bc * P1 * H_), 64, 0, stream>>>(XQ, XK, XV, T1U, b0);
  }

  // ---- ti = merge(t1u) @ Wt + bt
  {
    const int n4 = B_ * P1 * NCOL / 4;
    cast_f32_bf16<<<dim3((n4 + 255) / 256), 256, 0, stream>>>(T1U, T1Ub, n4);
    dim3 g((B_ * P1 + 127) / 128, DIMX / 128);
    gemm_mfma_bt<<<g, 256, 0, stream>>>(T1Ub, WtT, bt, TIU, B_ * P1, DIMX, NCOL);
  }
  // ---- q2 = ti@Wq, v2 = ti@Wk, k2 = ti@Wv
  {
    const int n4 = B_ * P1 * DIMX / 4;
    cast_f32_bf16<<<dim3((n4 + 255) / 256), 256, 0, stream>>>(TIU, TIUb, n4);
    dim3 g((B_ * P1 + 127) / 128, NCOL / 128);
    gemm_mfma_bt<<<g, 256, 0, stream>>>(TIUb, WqT, bq, Q2U, B_ * P1, NCOL, DIMX);
    gemm_mfma_bt<<<g, 256, 0, stream>>>(TIUb, WkT, bk, V2U, B_ * P1, NCOL, DIMX);
    gemm_mfma_bt<<<g, 256, 0, stream>>>(TIUb, WvT, bv, K2U, B_ * P1, NCOL, DIMX);
  }

  // ---- stage-2 attentions -> FULL9 rows 1..8
  xi0_scores_kernel<<<dim3(B_ * H_, 25), 256, 0, stream>>>(Q2U, K2U, Wmat);
  xi0_reduce_kernel<<<dim3(B_ * H_), 256, 0, stream>>>(Wmat, V2U, FULL9);
  stage2_xi_kernel<<<dim3(B_ * H_ * 7), 256, 0, stream>>>(Q2U, K2U, V2U, FULL9);

  // ---- final projection on the 9 unique rows per batch
  {
    const int n4 = B_ * 9 * NCOL / 4;
    cast_f32_bf16<<<dim3((n4 + 255) / 256), 256, 0, stream>>>(FULL9, FULL9b, n4);
    dim3 g((B_ * 9 + 127) / 128, DIMX / 128);
    gemm_mfma_bt<<<g, 256, 0, stream>>>(FULL9b, WfT, bf, OUT9, B_ * 9, DIMX, NCOL);
  }

  // ---- broadcast to the full (B, 1569, 768) output
  {
    const int total4 = B_ * SEQ * (DIMX / 4);
    bcast_kernel<<<dim3((total4 + 255) / 256), 256, 0, stream>>>(OUT9, out);
  }
}

// Round 4
// 1071.179 us; speedup vs baseline: 3.9236x; 1.6565x over previous
//
#include <hip/hip_runtime.h>
#include <math.h>

// Problem constants
#define B_    8
#define SEQ   1569      // 1 + 196*8
#define DIMX  768
#define H_    12
#define D3    192       // head dim slice (3*DH)
#define F_    8
#define NP    196
#define P1    195       // patches kept per frame
#define NCOL  2304      // 3*DIM
#define RSCALE (1.0f/96.0f)
#define NCHUNK 16       // cls split-K chunks
#define CH     99       // keys per chunk (16*99 >= 1569)
#define CLS_STRIDE 196  // 192 o + m + l (+pad)

typedef __bf16 bf16_t;
typedef bf16_t bf16x8 __attribute__((ext_vector_type(8)));
typedef float  f32x4  __attribute__((ext_vector_type(4)));

// ---------------- block reduction helpers (blockDim == 256) ----------------
__device__ __forceinline__ float block_max256(float v, float* red) {
  #pragma unroll
  for (int o = 32; o > 0; o >>= 1) v = fmaxf(v, __shfl_xor(v, o, 64));
  __syncthreads();
  if ((threadIdx.x & 63) == 0) red[threadIdx.x >> 6] = v;
  __syncthreads();
  return fmaxf(fmaxf(red[0], red[1]), fmaxf(red[2], red[3]));
}

__device__ __forceinline__ float block_sum256(float v, float* red) {
  #pragma unroll
  for (int o = 32; o > 0; o >>= 1) v += __shfl_xor(v, o, 64);
  __syncthreads();
  if ((threadIdx.x & 63) == 0) red[threadIdx.x >> 6] = v;
  __syncthreads();
  return red[0] + red[1] + red[2] + red[3];
}

// ---------------- cast fp32 -> bf16 (vector of 4) ----------------
__global__ __launch_bounds__(256) void cast_f32_bf16(
    const float* __restrict__ in, bf16_t* __restrict__ out, int n4) {
  const int i = blockIdx.x * 256 + threadIdx.x;
  if (i >= n4) return;
  const float4 v = ((const float4*)in)[i];
  bf16_t o4[4] = {(bf16_t)v.x, (bf16_t)v.y, (bf16_t)v.z, (bf16_t)v.w};
  ((uint2*)out)[i] = *(uint2*)o4;
}

// ---------------- transpose + cast: W (K x N fp32) -> WT (N x K bf16) -------
__global__ __launch_bounds__(256) void transpose_cast(
    const float* __restrict__ W, bf16_t* __restrict__ WT, int Kd, int Nd) {
  __shared__ float t[32][33];
  const int bn = blockIdx.x * 32;
  const int bk = blockIdx.y * 32;
  const int tx = threadIdx.x & 31, ty = threadIdx.x >> 5;  // 32 x 8
  #pragma unroll
  for (int i = 0; i < 32; i += 8)
    t[ty + i][tx] = W[(size_t)(bk + ty + i) * Nd + bn + tx];
  __syncthreads();
  #pragma unroll
  for (int i = 0; i < 32; i += 8)
    WT[(size_t)(bn + ty + i) * Kd + bk + tx] = (bf16_t)t[tx][ty + i];
}

// ---------------- bf16 MFMA GEMM: C = A @ BT^T + bias ----------------
// A: M x K bf16 row-major. BT: N x K bf16 row-major (i.e. W transposed).
// bias: N fp32. C: M x N fp32. K % 32 == 0, N % 128 == 0, M arbitrary.
__global__ __launch_bounds__(256) void gemm_mfma_bt(
    const bf16_t* __restrict__ A, const bf16_t* __restrict__ BT,
    const float* __restrict__ bias, float* __restrict__ C,
    int M, int N, int K) {
  __shared__ bf16_t As[128][32];
  __shared__ bf16_t Bs[128][32];
  const int tid  = threadIdx.x;
  const int row0 = blockIdx.x * 128;
  const int col0 = blockIdx.y * 128;
  const int wave = tid >> 6;
  const int lane = tid & 63;
  const int m0 = (wave & 1) * 64;
  const int n0 = (wave >> 1) * 64;

  f32x4 acc[4][4] = {};

  for (int k0 = 0; k0 < K; k0 += 32) {
    #pragma unroll
    for (int i = 0; i < 2; ++i) {
      const int chunk = tid * 2 + i;   // 0..511 -> 128 rows x 4 segs of 16B
      const int r = chunk >> 2;
      const int seg = chunk & 3;
      int ar = row0 + r; if (ar >= M) ar = M - 1;   // clamp (masked on store)
      *(uint4*)&As[r][seg * 8] =
          *(const uint4*)(A + (size_t)ar * K + k0 + seg * 8);
      *(uint4*)&Bs[r][seg * 8] =
          *(const uint4*)(BT + (size_t)(col0 + r) * K + k0 + seg * 8);
    }
    __syncthreads();

    const int fr = lane & 15, k8 = (lane >> 4) * 8;
    bf16x8 af[4], bfr[4];
    #pragma unroll
    for (int i = 0; i < 4; ++i) {
      af[i]  = *(const bf16x8*)&As[m0 + i * 16 + fr][k8];
      bfr[i] = *(const bf16x8*)&Bs[n0 + i * 16 + fr][k8];
    }
    #pragma unroll
    for (int i = 0; i < 4; ++i)
      #pragma unroll
      for (int j = 0; j < 4; ++j)
        acc[i][j] = __builtin_amdgcn_mfma_f32_16x16x32_bf16(
            af[i], bfr[j], acc[i][j], 0, 0, 0);
    __syncthreads();
  }

  // C/D layout: col = lane&15, row = (lane>>4)*4 + reg
  const int cc = lane & 15, cr4 = (lane >> 4) * 4;
  #pragma unroll
  for (int i = 0; i < 4; ++i) {
    #pragma unroll
    for (int j = 0; j < 4; ++j) {
      const int col = col0 + n0 + j * 16 + cc;
      const float bcol = bias[col];
      #pragma unroll
      for (int reg = 0; reg < 4; ++reg) {
        const int r = row0 + m0 + i * 16 + cr4 + reg;
        if (r < M) C[(size_t)r * N + col] = acc[i][j][reg] + bcol;
      }
    }
  }
}

// ---------------- cls attention, split over keys ----------------
// grid (Bc*H, NCHUNK). Each block: ~CH keys, local softmax partials
// (m_c, l_c, unnormalized o_c[192]) -> CLSP[b][h][c][*] (b global).
__global__ __launch_bounds__(256) void cls_part_kernel(
    const float* __restrict__ XQ, const float* __restrict__ XK,
    const float* __restrict__ XV, float* __restrict__ CLSP, int b0) {
  const int h  = blockIdx.x % H_;
  const int bl = blockIdx.x / H_;
  const int b  = b0 + bl;
  const int c  = blockIdx.y;
  const int t0 = c * CH;
  const int tend = (t0 + CH < SEQ) ? t0 + CH : SEQ;
  __shared__ float qs[D3];
  __shared__ float sc[CH];
  __shared__ float red[4];
  const int tid = threadIdx.x;

  const float* Qr = XQ + (size_t)bl * SEQ * NCOL + h * D3;
  if (tid < 48) ((float4*)qs)[tid] = ((const float4*)Qr)[tid];
  __syncthreads();

  float lmax = -1e30f;
  for (int t = t0 + tid; t < tend; t += 256) {
    const float* kr = XK + ((size_t)bl * SEQ + t) * NCOL + h * D3;
    float acc = 0.f;
    #pragma unroll 4
    for (int d = 0; d < D3; d += 4) {
      const float4 k4 = *(const float4*)(kr + d);
      acc = fmaf(qs[d], k4.x, acc);
      acc = fmaf(qs[d + 1], k4.y, acc);
      acc = fmaf(qs[d + 2], k4.z, acc);
      acc = fmaf(qs[d + 3], k4.w, acc);
    }
    acc *= RSCALE;
    sc[t - t0] = acc;
    lmax = fmaxf(lmax, acc);
  }
  const float m = block_max256(lmax, red);
  float lsum = 0.f;
  for (int t = t0 + tid; t < tend; t += 256) {
    const float e = expf(sc[t - t0] - m);
    sc[t - t0] = e;
    lsum += e;
  }
  const float L = block_sum256(lsum, red);
  __syncthreads();

  float* P = CLSP + ((size_t)(b * H_ + h) * NCHUNK + c) * CLS_STRIDE;
  if (tid < D3) {
    float acc = 0.f;
    const float* vbase = XV + ((size_t)bl * SEQ + t0) * NCOL + h * D3 + tid;
    for (int t = t0; t < tend; ++t)
      acc = fmaf(sc[t - t0], vbase[(size_t)(t - t0) * NCOL], acc);
    P[tid] = acc;
  }
  if (tid == 192) P[192] = m;
  if (tid == 193) P[193] = L;
}

// ---------------- cls combine: merge NCHUNK partials ----------------
__global__ __launch_bounds__(256) void cls_combine_kernel(
    const float* __restrict__ CLSP, float* __restrict__ FULL9) {
  const int bh = blockIdx.x;
  const int tid = threadIdx.x;
  const float* P = CLSP + (size_t)bh * NCHUNK * CLS_STRIDE;

  float M = -1e30f;
  #pragma unroll
  for (int c = 0; c < NCHUNK; ++c) M = fmaxf(M, P[c * CLS_STRIDE + 192]);
  float L = 0.f;
  float w[NCHUNK];
  #pragma unroll
  for (int c = 0; c < NCHUNK; ++c) {
    w[c] = expf(P[c * CLS_STRIDE + 192] - M);
    L += P[c * CLS_STRIDE + 193] * w[c];
  }
  if (tid < D3) {
    float acc = 0.f;
    #pragma unroll
    for (int c = 0; c < NCHUNK; ++c)
      acc = fmaf(w[c], P[c * CLS_STRIDE + tid], acc);
    const int b = bh / H_, h = bh % H_;
    FULL9[((size_t)b * 9 + 0) * NCOL + h * D3 + tid] = acc / L;
  }
}

// ---------------- temporal attention per (b, h, patch) ----------------
__global__ __launch_bounds__(64) void temporal_kernel(
    const float* __restrict__ XQ, const float* __restrict__ XK,
    const float* __restrict__ XV, float* __restrict__ T1U, int b0) {
  const int id = blockIdx.x;
  const int pi = id % P1;
  const int h  = (id / P1) % H_;
  const int bl = id / (P1 * H_);
  const int b  = b0 + bl;
  __shared__ float qs[8][196], ks[8][196], vs[8][196];
  __shared__ float wg[8];
  const int tid = threadIdx.x;  // 64

  #pragma unroll
  for (int i = 0; i < 6; ++i) {
    const int idx = tid + 64 * i;      // 0..383
    const int f = idx / 48, d4 = idx % 48;
    const size_t base = ((size_t)bl * SEQ + (size_t)f * NP + pi + 2) * NCOL + h * D3 + d4 * 4;
    *(float4*)&qs[f][d4 * 4] = *(const float4*)(XQ + base);
    *(float4*)&ks[f][d4 * 4] = *(const float4*)(XV + base);  // keys from Wv proj
    *(float4*)&vs[f][d4 * 4] = *(const float4*)(XK + base);  // values from Wk proj
  }
  __syncthreads();

  const int f = tid >> 3, g = tid & 7;
  float s = 0.f;
  for (int d = 0; d < D3; d += 4) {
    const float4 a4 = *(const float4*)&qs[f][d];
    const float4 b4 = *(const float4*)&ks[g][d];
    s = fmaf(a4.x, b4.x, s); s = fmaf(a4.y, b4.y, s);
    s = fmaf(a4.z, b4.z, s); s = fmaf(a4.w, b4.w, s);
  }
  s *= RSCALE;

  float m = s;
  #pragma unroll
  for (int o = 1; o < 8; o <<= 1) m = fmaxf(m, __shfl_xor(m, o, 64));
  const float e = expf(s - m);
  float sum = e;
  #pragma unroll
  for (int o = 1; o < 8; o <<= 1) sum += __shfl_xor(sum, o, 64);
  float a = e / sum;
  #pragma unroll
  for (int o = 8; o < 64; o <<= 1) a += __shfl_xor(a, o, 64);
  if (tid < 8) wg[tid] = a;
  __syncthreads();

  #pragma unroll
  for (int i = 0; i < 3; ++i) {
    const int d = tid + 64 * i;
    float o = 0.f;
    #pragma unroll
    for (int gg = 0; gg < 8; ++gg) o = fmaf(wg[gg], vs[gg][d], o);
    T1U[((size_t)b * P1 + pi) * NCOL + h * D3 + d] = o;
  }
}

// ---------------- stage-2, xi = 0: scores, 8 queries per block ----------
__global__ __launch_bounds__(256) void xi0_scores_kernel(
    const float* __restrict__ Q2U, const float* __restrict__ K2U,
    float* __restrict__ Wmat) {
  const int bh = blockIdx.x;           // b*H + h
  const int h  = bh % H_, b = bh / H_;
  const int q0 = blockIdx.y * 8;
  __shared__ float qs[8][D3];
  __shared__ float red[4];
  const int tid = threadIdx.x;

  for (int idx = tid; idx < 8 * 48; idx += 256) {
    const int qi = idx / 48, d4 = idx % 48;
    int rq = q0 + qi; if (rq >= P1) rq = P1 - 1;
    *(float4*)&qs[qi][d4 * 4] =
        *(const float4*)(Q2U + ((size_t)(b * P1 + rq)) * NCOL + h * D3 + d4 * 4);
  }
  __syncthreads();

  float dot[8] = {0.f, 0.f, 0.f, 0.f, 0.f, 0.f, 0.f, 0.f};
  if (tid < P1) {
    const float* kr = K2U + ((size_t)(b * P1 + tid)) * NCOL + h * D3;
    for (int d = 0; d < D3; d += 4) {
      const float4 k4 = *(const float4*)(kr + d);
      #pragma unroll
      for (int qi = 0; qi < 8; ++qi) {
        const float4 q4 = *(const float4*)&qs[qi][d];  // LDS broadcast
        dot[qi] = fmaf(k4.x, q4.x, dot[qi]);
        dot[qi] = fmaf(k4.y, q4.y, dot[qi]);
        dot[qi] = fmaf(k4.z, q4.z, dot[qi]);
        dot[qi] = fmaf(k4.w, q4.w, dot[qi]);
      }
    }
  }
  #pragma unroll
  for (int qi = 0; qi < 8; ++qi) {
    const int rq = q0 + qi;
    const float v = (tid < P1) ? dot[qi] * RSCALE : -1e30f;
    const float m = block_max256(v, red);
    const float f = (tid < P1) ? expf(v - m) * ((tid == 0) ? 2.f : 1.f) : 0.f;
    const float D = block_sum256(f, red);
    if (tid < P1 && rq < P1)
      Wmat[((size_t)bh * P1 + rq) * P1 + tid] = ((rq == 0) ? 2.f : 1.f) * f / D;
  }
}

// ---------------- stage-2, xi = 0: reduce weights over queries, apply V ------
__global__ __launch_bounds__(256) void xi0_reduce_kernel(
    const float* __restrict__ Wmat, const float* __restrict__ V2U,
    float* __restrict__ FULL9) {
  const int bh = blockIdx.x;
  const int h = bh % H_, b = bh / H_;
  __shared__ float g[P1];
  const int tid = threadIdx.x;
  if (tid < P1) {
    float s = 0.f;
    for (int r = 0; r < P1; ++r) s += Wmat[((size_t)bh * P1 + r) * P1 + tid];
    g[tid] = s;
  }
  __syncthreads();
  if (tid < D3) {
    float acc = 0.f;
    const float* vbase = V2U + (size_t)b * P1 * NCOL + h * D3 + tid;
    for (int k = 0; k < P1; ++k) acc = fmaf(g[k], vbase[(size_t)k * NCOL], acc);
    FULL9[((size_t)b * 9 + 1) * NCOL + h * D3 + tid] = acc;
  }
}

// ---------------- stage-2, xi = 1..7: 195(+dup row xi) queries over 8 keys ----
__global__ __launch_bounds__(256) void stage2_xi_kernel(
    const float* __restrict__ Q2U, const float* __restrict__ K2U,
    const float* __restrict__ V2U, float* __restrict__ FULL9) {
  const int xi = 1 + blockIdx.x % 7;
  const int h  = (blockIdx.x / 7) % H_;
  const int b  = blockIdx.x / (7 * H_);
  __shared__ float Ks[8][196], Vs[8][196], Qs[32][196];
  __shared__ float P[32][8];
  const int tid = threadIdx.x;

  for (int idx = tid; idx < 384; idx += 256) {
    const int k = idx / 48, d4 = idx % 48;
    const size_t base = ((size_t)(b * P1 + xi + k)) * NCOL + h * D3 + d4 * 4;
    *(float4*)&Ks[k][d4 * 4] = *(const float4*)(K2U + base);
    *(float4*)&Vs[k][d4 * 4] = *(const float4*)(V2U + base);
  }

  float acc = 0.f;  // for d = tid (tid < 192)
  for (int c = 0; c < 7; ++c) {
    __syncthreads();
    for (int idx = tid; idx < 32 * 48; idx += 256) {
      const int qr = idx / 48, d4 = idx % 48;
      const int rq = c * 32 + qr;
      float4 v = make_float4(0.f, 0.f, 0.f, 0.f);
      if (rq < P1)
        v = *(const float4*)(Q2U + ((size_t)(b * P1 + rq)) * NCOL + h * D3 + d4 * 4);
      *(float4*)&Qs[qr][d4 * 4] = v;
    }
    __syncthreads();
    const int grp = tid >> 3, k = tid & 7;
    float dot = 0.f;
    for (int d = 0; d < D3; d += 4) {
      const float4 a4 = *(const float4*)&Qs[grp][d];
      const float4 b4 = *(const float4*)&Ks[k][d];
      dot = fmaf(a4.x, b4.x, dot); dot = fmaf(a4.y, b4.y, dot);
      dot = fmaf(a4.z, b4.z, dot); dot = fmaf(a4.w, b4.w, dot);
    }
    dot *= RSCALE;
    float m = dot;
    #pragma unroll
    for (int o = 1; o < 8; o <<= 1) m = fmaxf(m, __shfl_xor(m, o, 64));
    const float e = expf(dot - m);
    float s = e;
    #pragma unroll
    for (int o = 1; o < 8; o <<= 1) s += __shfl_xor(s, o, 64);
    P[grp][k] = e / s;
    __syncthreads();
    if (tid < D3) {
      #pragma unroll 4
      for (int g2 = 0; g2 < 32; ++g2) {
        const int rq2 = c * 32 + g2;
        if (rq2 < P1) {
          const float mult = (rq2 == xi) ? 2.f : 1.f;
          float o = 0.f;
          #pragma unroll
          for (int kk = 0; kk < 8; ++kk) o = fmaf(P[g2][kk], Vs[kk][tid], o);
          acc = fmaf(mult, o, acc);
        }
      }
    }
  }
  if (tid < D3) FULL9[((size_t)b * 9 + 1 + xi) * NCOL + h * D3 + tid] = acc;
}

// ---------------- broadcast OUT9 -> full output ----------------
__global__ __launch_bounds__(256) void bcast_kernel(
    const float* __restrict__ OUT9, float* __restrict__ out) {
  const int idx = blockIdx.x * 256 + threadIdx.x;  // over float4s
  const int total = B_ * SEQ * (DIMX / 4);
  if (idx >= total) return;
  const int d4 = idx % (DIMX / 4);
  const int bs = idx / (DIMX / 4);
  const int s = bs % SEQ;
  const int b = bs / SEQ;
  const int row = (s == 0) ? 0 : 1 + ((s - 1) & 7);
  ((float4*)out)[idx] = ((const float4*)OUT9)[(size_t)(b * 9 + row) * (DIMX / 4) + d4];
}

// ---------------- launch ----------------
extern "C" void kernel_launch(void* const* d_in, const int* in_sizes, int n_in,
                              void* d_out, int out_size, void* d_ws, size_t ws_size,
                              hipStream_t stream) {
  const float* x  = (const float*)d_in[0];
  const float* Wq = (const float*)d_in[1];
  const float* bq = (const float*)d_in[2];
  const float* Wk = (const float*)d_in[3];
  const float* bk = (const float*)d_in[4];
  const float* Wv = (const float*)d_in[5];
  const float* bv = (const float*)d_in[6];
  const float* Wt = (const float*)d_in[7];
  const float* bt = (const float*)d_in[8];
  const float* Wf = (const float*)d_in[9];
  const float* bf = (const float*)d_in[10];
  float* out = (float*)d_out;
  (void)in_sizes; (void)n_in; (void)out_size;

  char* ws = (char*)d_ws;
  size_t off = 0;
  auto alloc_f32 = [&](size_t elems) {
    size_t a = (off + 63) & ~(size_t)63;
    off = a + elems * sizeof(float);
    return (float*)(ws + a);
  };
  auto alloc_bf16 = [&](size_t elems) {
    size_t a = (off + 63) & ~(size_t)63;
    off = a + elems * sizeof(bf16_t);
    return (bf16_t*)(ws + a);
  };

  float*  T1U    = alloc_f32((size_t)B_ * P1 * NCOL);
  float*  TIU    = alloc_f32((size_t)B_ * P1 * DIMX);
  float*  Q2U    = alloc_f32((size_t)B_ * P1 * NCOL);
  float*  V2U    = alloc_f32((size_t)B_ * P1 * NCOL);
  float*  K2U    = alloc_f32((size_t)B_ * P1 * NCOL);
  float*  FULL9  = alloc_f32((size_t)B_ * 9 * NCOL);
  float*  OUT9   = alloc_f32((size_t)B_ * 9 * DIMX);
  float*  Wmat   = alloc_f32((size_t)B_ * H_ * P1 * P1);
  float*  CLSP   = alloc_f32((size_t)B_ * H_ * NCHUNK * CLS_STRIDE);
  bf16_t* WqT    = alloc_bf16((size_t)NCOL * DIMX);
  bf16_t* WkT    = alloc_bf16((size_t)NCOL * DIMX);
  bf16_t* WvT    = alloc_bf16((size_t)NCOL * DIMX);
  bf16_t* WtT    = alloc_bf16((size_t)DIMX * NCOL);
  bf16_t* WfT    = alloc_bf16((size_t)DIMX * NCOL);
  bf16_t* T1Ub   = alloc_bf16((size_t)B_ * P1 * NCOL);
  bf16_t* TIUb   = alloc_bf16((size_t)B_ * P1 * DIMX);
  bf16_t* FULL9b = alloc_bf16((size_t)B_ * 9 * NCOL);

  // chunked stage-1 buffers
  const size_t remain = (ws_size > off) ? (ws_size - off) : 0;
  int Bc = 8;
  while (Bc > 1 &&
         (size_t)Bc * SEQ * (3 * NCOL * sizeof(float) + DIMX * sizeof(bf16_t)) + 256 > remain)
    Bc >>= 1;
  float*  XQ = alloc_f32((size_t)Bc * SEQ * NCOL);
  float*  XK = alloc_f32((size_t)Bc * SEQ * NCOL);
  float*  XV = alloc_f32((size_t)Bc * SEQ * NCOL);
  bf16_t* xb = alloc_bf16((size_t)Bc * SEQ * DIMX);

  // ---- weight transposes (bf16)
  transpose_cast<<<dim3(NCOL / 32, DIMX / 32), 256, 0, stream>>>(Wq, WqT, DIMX, NCOL);
  transpose_cast<<<dim3(NCOL / 32, DIMX / 32), 256, 0, stream>>>(Wk, WkT, DIMX, NCOL);
  transpose_cast<<<dim3(NCOL / 32, DIMX / 32), 256, 0, stream>>>(Wv, WvT, DIMX, NCOL);
  transpose_cast<<<dim3(DIMX / 32, NCOL / 32), 256, 0, stream>>>(Wt, WtT, NCOL, DIMX);
  transpose_cast<<<dim3(DIMX / 32, NCOL / 32), 256, 0, stream>>>(Wf, WfT, NCOL, DIMX);

  // ---- stage 1 (chunked over batch): cast x, bf16 GEMMs, cls + temporal attn
  for (int b0 = 0; b0 < B_; b0 += Bc) {
    const int Mrows = Bc * SEQ;
    const int n4 = Mrows * DIMX / 4;
    cast_f32_bf16<<<dim3((n4 + 255) / 256), 256, 0, stream>>>(
        x + (size_t)b0 * SEQ * DIMX, xb, n4);
    dim3 g1((Mrows + 127) / 128, NCOL / 128);
    gemm_mfma_bt<<<g1, 256, 0, stream>>>(xb, WqT, bq, XQ, Mrows, NCOL, DIMX);
    gemm_mfma_bt<<<g1, 256, 0, stream>>>(xb, WkT, bk, XK, Mrows, NCOL, DIMX);
    gemm_mfma_bt<<<g1, 256, 0, stream>>>(xb, WvT, bv, XV, Mrows, NCOL, DIMX);
    cls_part_kernel<<<dim3(Bc * H_, NCHUNK), 256, 0, stream>>>(XQ, XK, XV, CLSP, b0);
    temporal_kernel<<<dim3(Bc * P1 * H_), 64, 0, stream>>>(XQ, XK, XV, T1U, b0);
  }
  cls_combine_kernel<<<dim3(B_ * H_), 256, 0, stream>>>(CLSP, FULL9);

  // ---- ti = merge(t1u) @ Wt + bt
  {
    const int n4 = B_ * P1 * NCOL / 4;
    cast_f32_bf16<<<dim3((n4 + 255) / 256), 256, 0, stream>>>(T1U, T1Ub, n4);
    dim3 g((B_ * P1 + 127) / 128, DIMX / 128);
    gemm_mfma_bt<<<g, 256, 0, stream>>>(T1Ub, WtT, bt, TIU, B_ * P1, DIMX, NCOL);
  }
  // ---- q2 = ti@Wq, v2 = ti@Wk, k2 = ti@Wv
  {
    const int n4 = B_ * P1 * DIMX / 4;
    cast_f32_bf16<<<dim3((n4 + 255) / 256), 256, 0, stream>>>(TIU, TIUb, n4);
    dim3 g((B_ * P1 + 127) / 128, NCOL / 128);
    gemm_mfma_bt<<<g, 256, 0, stream>>>(TIUb, WqT, bq, Q2U, B_ * P1, NCOL, DIMX);
    gemm_mfma_bt<<<g, 256, 0, stream>>>(TIUb, WkT, bk, V2U, B_ * P1, NCOL, DIMX);
    gemm_mfma_bt<<<g, 256, 0, stream>>>(TIUb, WvT, bv, K2U, B_ * P1, NCOL, DIMX);
  }

  // ---- stage-2 attentions -> FULL9 rows 1..8
  xi0_scores_kernel<<<dim3(B_ * H_, 25), 256, 0, stream>>>(Q2U, K2U, Wmat);
  xi0_reduce_kernel<<<dim3(B_ * H_), 256, 0, stream>>>(Wmat, V2U, FULL9);
  stage2_xi_kernel<<<dim3(B_ * H_ * 7), 256, 0, stream>>>(Q2U, K2U, V2U, FULL9);

  // ---- final projection on the 9 unique rows per batch
  {
    const int n4 = B_ * 9 * NCOL / 4;
    cast_f32_bf16<<<dim3((n4 + 255) / 256), 256, 0, stream>>>(FULL9, FULL9b, n4);
    dim3 g((B_ * 9 + 127) / 128, DIMX / 128);
    gemm_mfma_bt<<<g, 256, 0, stream>>>(FULL9b, WfT, bf, OUT9, B_ * 9, DIMX, NCOL);
  }

  // ---- broadcast to the full (B, 1569, 768) output
  {
    const int total4 = B_ * SEQ * (DIMX / 4);
    bcast_kernel<<<dim3((total4 + 255) / 256), 256, 0, stream>>>(OUT9, out);
  }
}

// Round 5
// 824.822 us; speedup vs baseline: 5.0955x; 1.2987x over previous
//
#include <hip/hip_runtime.h>
#include <math.h>

// Problem constants
#define B_    8
#define SEQ   1569      // 1 + 196*8
#define DIMX  768
#define H_    12
#define D3    192       // head dim slice (3*DH)
#define F_    8
#define NP    196
#define P1    195       // patches kept per frame
#define NCOL  2304      // 3*DIM
#define RSCALE (1.0f/96.0f)
#define NCHUNK 16       // cls split-K chunks
#define CH     99       // keys per chunk (16*99 >= 1569)
#define CLS_STRIDE 196  // 192 o + m + l (+pad)

typedef __bf16 bf16_t;
typedef bf16_t bf16x8 __attribute__((ext_vector_type(8)));
typedef float  f32x4  __attribute__((ext_vector_type(4)));

// async global->LDS, 16B per lane; LDS dest = wave-uniform base + lane*16
__device__ __forceinline__ void load_lds16(const bf16_t* g, bf16_t* l) {
  __builtin_amdgcn_global_load_lds(
      (const __attribute__((address_space(1))) void*)g,
      (__attribute__((address_space(3))) void*)l, 16, 0, 0);
}

// ---------------- block reduction helpers (blockDim == 256) ----------------
__device__ __forceinline__ float block_max256(float v, float* red) {
  #pragma unroll
  for (int o = 32; o > 0; o >>= 1) v = fmaxf(v, __shfl_xor(v, o, 64));
  __syncthreads();
  if ((threadIdx.x & 63) == 0) red[threadIdx.x >> 6] = v;
  __syncthreads();
  return fmaxf(fmaxf(red[0], red[1]), fmaxf(red[2], red[3]));
}

__device__ __forceinline__ float block_sum256(float v, float* red) {
  #pragma unroll
  for (int o = 32; o > 0; o >>= 1) v += __shfl_xor(v, o, 64);
  __syncthreads();
  if ((threadIdx.x & 63) == 0) red[threadIdx.x >> 6] = v;
  __syncthreads();
  return red[0] + red[1] + red[2] + red[3];
}

// ---------------- cast fp32 -> bf16 (vector of 4) ----------------
__global__ __launch_bounds__(256) void cast_f32_bf16(
    const float* __restrict__ in, bf16_t* __restrict__ out, int n4) {
  const int i = blockIdx.x * 256 + threadIdx.x;
  if (i >= n4) return;
  const float4 v = ((const float4*)in)[i];
  bf16_t o4[4] = {(bf16_t)v.x, (bf16_t)v.y, (bf16_t)v.z, (bf16_t)v.w};
  ((uint2*)out)[i] = *(uint2*)o4;
}

// ---------------- transpose + cast: W (K x N fp32) -> WT (N x K bf16) -------
__global__ __launch_bounds__(256) void transpose_cast(
    const float* __restrict__ W, bf16_t* __restrict__ WT, int Kd, int Nd) {
  __shared__ float t[32][33];
  const int bn = blockIdx.x * 32;
  const int bk = blockIdx.y * 32;
  const int tx = threadIdx.x & 31, ty = threadIdx.x >> 5;  // 32 x 8
  #pragma unroll
  for (int i = 0; i < 32; i += 8)
    t[ty + i][tx] = W[(size_t)(bk + ty + i) * Nd + bn + tx];
  __syncthreads();
  #pragma unroll
  for (int i = 0; i < 32; i += 8)
    WT[(size_t)(bn + ty + i) * Kd + bk + tx] = (bf16_t)t[tx][ty + i];
}

// ---------------- bf16 MFMA GEMM: C = A @ BT^T + bias ----------------
// A: M x K bf16 row-major. BT: N x K bf16 row-major. bias: N fp32.
// C: M x N, fp32 or bf16 per outBf16. K%32==0, N%128==0, M arbitrary.
// global_load_lds staging (m97 pattern).
__global__ __launch_bounds__(256) void gemm_mfma_bt(
    const bf16_t* __restrict__ A, const bf16_t* __restrict__ BT,
    const float* __restrict__ bias, void* __restrict__ C,
    int M, int N, int K, int outBf16) {
  __shared__ bf16_t As[128][32];
  __shared__ bf16_t Bs[128][32];
  const int tid  = threadIdx.x;
  const int wave = tid >> 6, lane = tid & 63;
  const int row0 = blockIdx.x * 128, col0 = blockIdx.y * 128;
  const int lrow = lane >> 2, lseg = lane & 3;

  int r0 = row0 + wave * 32 + lrow;
  int r1 = r0 + 16;
  if (r0 >= M) r0 = M - 1;
  if (r1 >= M) r1 = M - 1;
  const bf16_t* Ap0 = A + (size_t)r0 * K + lseg * 8;
  const bf16_t* Ap1 = A + (size_t)r1 * K + lseg * 8;
  const bf16_t* Bp0 = BT + (size_t)(col0 + wave * 32 + lrow) * K + lseg * 8;
  const bf16_t* Bp1 = Bp0 + (size_t)16 * K;
  bf16_t* lA0 = &As[wave * 32][0];
  bf16_t* lA1 = &As[wave * 32 + 16][0];
  bf16_t* lB0 = &Bs[wave * 32][0];
  bf16_t* lB1 = &Bs[wave * 32 + 16][0];

  const int m0 = (wave & 1) * 64, n0 = (wave >> 1) * 64;
  const int fr = lane & 15, k8 = (lane >> 4) * 8;
  f32x4 acc[4][4] = {};

  for (int k0 = 0; k0 < K; k0 += 32) {
    load_lds16(Ap0 + k0, lA0);
    load_lds16(Ap1 + k0, lA1);
    load_lds16(Bp0 + k0, lB0);
    load_lds16(Bp1 + k0, lB1);
    __syncthreads();

    bf16x8 af[4], bfr[4];
    #pragma unroll
    for (int i = 0; i < 4; ++i) {
      af[i]  = *(const bf16x8*)&As[m0 + i * 16 + fr][k8];
      bfr[i] = *(const bf16x8*)&Bs[n0 + i * 16 + fr][k8];
    }
    #pragma unroll
    for (int i = 0; i < 4; ++i)
      #pragma unroll
      for (int j = 0; j < 4; ++j)
        acc[i][j] = __builtin_amdgcn_mfma_f32_16x16x32_bf16(
            af[i], bfr[j], acc[i][j], 0, 0, 0);
    __syncthreads();
  }

  const int cc = lane & 15, cr4 = (lane >> 4) * 4;
  #pragma unroll
  for (int i = 0; i < 4; ++i) {
    #pragma unroll
    for (int j = 0; j < 4; ++j) {
      const int col = col0 + n0 + j * 16 + cc;
      const float bcol = bias[col];
      #pragma unroll
      for (int reg = 0; reg < 4; ++reg) {
        const int r = row0 + m0 + i * 16 + cr4 + reg;
        if (r < M) {
          const float v = acc[i][j][reg] + bcol;
          if (outBf16) ((bf16_t*)C)[(size_t)r * N + col] = (bf16_t)v;
          else         ((float*)C)[(size_t)r * N + col] = v;
        }
      }
    }
  }
}

// ---------------- xi0 scores via MFMA: S = RSCALE * Q2 @ K2^T per (b,h) ------
// grid (2, 2, 96). A/B rows have stride NCOL; M=N=P1, K=D3.
__global__ __launch_bounds__(256) void xi0_scores_mfma(
    const bf16_t* __restrict__ Q2b, const bf16_t* __restrict__ K2b,
    float* __restrict__ Smat) {
  __shared__ bf16_t As[128][32];
  __shared__ bf16_t Bs[128][32];
  const int tid  = threadIdx.x;
  const int wave = tid >> 6, lane = tid & 63;
  const int row0 = blockIdx.x * 128, col0 = blockIdx.y * 128;
  const int bh = blockIdx.z;
  const int b = bh / H_, h = bh % H_;
  const bf16_t* Abase = Q2b + (size_t)b * P1 * NCOL + h * D3;
  const bf16_t* Bbase = K2b + (size_t)b * P1 * NCOL + h * D3;
  const int lrow = lane >> 2, lseg = lane & 3;

  int r0 = row0 + wave * 32 + lrow;
  int r1 = r0 + 16;
  if (r0 >= P1) r0 = P1 - 1;
  if (r1 >= P1) r1 = P1 - 1;
  int c0 = col0 + wave * 32 + lrow;
  int c1 = c0 + 16;
  if (c0 >= P1) c0 = P1 - 1;
  if (c1 >= P1) c1 = P1 - 1;
  const bf16_t* Ap0 = Abase + (size_t)r0 * NCOL + lseg * 8;
  const bf16_t* Ap1 = Abase + (size_t)r1 * NCOL + lseg * 8;
  const bf16_t* Bp0 = Bbase + (size_t)c0 * NCOL + lseg * 8;
  const bf16_t* Bp1 = Bbase + (size_t)c1 * NCOL + lseg * 8;
  bf16_t* lA0 = &As[wave * 32][0];
  bf16_t* lA1 = &As[wave * 32 + 16][0];
  bf16_t* lB0 = &Bs[wave * 32][0];
  bf16_t* lB1 = &Bs[wave * 32 + 16][0];

  const int m0 = (wave & 1) * 64, n0 = (wave >> 1) * 64;
  const int fr = lane & 15, k8 = (lane >> 4) * 8;
  f32x4 acc[4][4] = {};

  for (int k0 = 0; k0 < D3; k0 += 32) {
    load_lds16(Ap0 + k0, lA0);
    load_lds16(Ap1 + k0, lA1);
    load_lds16(Bp0 + k0, lB0);
    load_lds16(Bp1 + k0, lB1);
    __syncthreads();
    bf16x8 af[4], bfr[4];
    #pragma unroll
    for (int i = 0; i < 4; ++i) {
      af[i]  = *(const bf16x8*)&As[m0 + i * 16 + fr][k8];
      bfr[i] = *(const bf16x8*)&Bs[n0 + i * 16 + fr][k8];
    }
    #pragma unroll
    for (int i = 0; i < 4; ++i)
      #pragma unroll
      for (int j = 0; j < 4; ++j)
        acc[i][j] = __builtin_amdgcn_mfma_f32_16x16x32_bf16(
            af[i], bfr[j], acc[i][j], 0, 0, 0);
    __syncthreads();
  }

  float* S = Smat + (size_t)bh * P1 * P1;
  const int cc = lane & 15, cr4 = (lane >> 4) * 4;
  #pragma unroll
  for (int i = 0; i < 4; ++i)
    #pragma unroll
    for (int j = 0; j < 4; ++j) {
      const int col = col0 + n0 + j * 16 + cc;
      #pragma unroll
      for (int reg = 0; reg < 4; ++reg) {
        const int r = row0 + m0 + i * 16 + cr4 + reg;
        if (r < P1 && col < P1) S[(size_t)r * P1 + col] = acc[i][j][reg] * RSCALE;
      }
    }
}

// ---------------- xi0 finish: row softmax stats, colsum, PV ----------------
__global__ __launch_bounds__(256) void xi0_finish_kernel(
    const float* __restrict__ Smat, const float* __restrict__ V2U,
    bf16_t* __restrict__ FULL9b) {
  const int bh = blockIdx.x;
  const int b = bh / H_, h = bh % H_;
  __shared__ float mrow[P1], inv_l[P1], g[P1];
  const float* S = Smat + (size_t)bh * P1 * P1;
  const int tid = threadIdx.x;

  if (tid < P1) {
    float m = -1e30f;
    for (int k = 0; k < P1; ++k) m = fmaxf(m, S[(size_t)tid * P1 + k]);
    float l = 0.f;
    for (int k = 0; k < P1; ++k)
      l += expf(S[(size_t)tid * P1 + k] - m) * ((k == 0) ? 2.f : 1.f);
    mrow[tid] = m;
    inv_l[tid] = ((tid == 0) ? 2.f : 1.f) / l;   // query-row multiplicity / denom
  }
  __syncthreads();
  if (tid < P1) {
    float s = 0.f;
    for (int r = 0; r < P1; ++r)
      s += expf(S[(size_t)r * P1 + tid] - mrow[r]) * inv_l[r];
    g[tid] = s * ((tid == 0) ? 2.f : 1.f);       // key-0 multiplicity
  }
  __syncthreads();
  if (tid < D3) {
    float acc = 0.f;
    const float* vbase = V2U + (size_t)b * P1 * NCOL + h * D3 + tid;
    for (int k = 0; k < P1; ++k) acc = fmaf(g[k], vbase[(size_t)k * NCOL], acc);
    FULL9b[((size_t)b * 9 + 1) * NCOL + h * D3 + tid] = (bf16_t)acc;
  }
}

// ---------------- cls attention, split over keys (bf16 inputs) --------------
__global__ __launch_bounds__(256) void cls_part_kernel(
    const bf16_t* __restrict__ XQ, const bf16_t* __restrict__ XK,
    const bf16_t* __restrict__ XV, float* __restrict__ CLSP, int b0) {
  const int h  = blockIdx.x % H_;
  const int bl = blockIdx.x / H_;
  const int b  = b0 + bl;
  const int c  = blockIdx.y;
  const int t0 = c * CH;
  const int tend = (t0 + CH < SEQ) ? t0 + CH : SEQ;
  __shared__ float qs[D3];
  __shared__ float sc[CH];
  __shared__ float red[4];
  const int tid = threadIdx.x;

  const bf16_t* Qr = XQ + (size_t)bl * SEQ * NCOL + h * D3;
  if (tid < 24) {
    const bf16x8 q8 = *(const bf16x8*)(Qr + tid * 8);
    #pragma unroll
    for (int m2 = 0; m2 < 8; ++m2) qs[tid * 8 + m2] = (float)q8[m2];
  }
  __syncthreads();

  float lmax = -1e30f;
  for (int t = t0 + tid; t < tend; t += 256) {
    const bf16_t* kr = XK + ((size_t)bl * SEQ + t) * NCOL + h * D3;
    float acc = 0.f;
    #pragma unroll 3
    for (int d = 0; d < D3; d += 8) {
      const bf16x8 k8 = *(const bf16x8*)(kr + d);
      #pragma unroll
      for (int m2 = 0; m2 < 8; ++m2) acc = fmaf(qs[d + m2], (float)k8[m2], acc);
    }
    acc *= RSCALE;
    sc[t - t0] = acc;
    lmax = fmaxf(lmax, acc);
  }
  const float m = block_max256(lmax, red);
  float lsum = 0.f;
  for (int t = t0 + tid; t < tend; t += 256) {
    const float e = expf(sc[t - t0] - m);
    sc[t - t0] = e;
    lsum += e;
  }
  const float L = block_sum256(lsum, red);
  __syncthreads();

  float* P = CLSP + ((size_t)(b * H_ + h) * NCHUNK + c) * CLS_STRIDE;
  if (tid < D3) {
    float acc = 0.f;
    const bf16_t* vbase = XV + ((size_t)bl * SEQ + t0) * NCOL + h * D3 + tid;
    for (int t = t0; t < tend; ++t)
      acc = fmaf(sc[t - t0], (float)vbase[(size_t)(t - t0) * NCOL], acc);
    P[tid] = acc;
  }
  if (tid == 192) P[192] = m;
  if (tid == 193) P[193] = L;
}

// ---------------- cls combine: merge NCHUNK partials ----------------
__global__ __launch_bounds__(256) void cls_combine_kernel(
    const float* __restrict__ CLSP, bf16_t* __restrict__ FULL9b) {
  const int bh = blockIdx.x;
  const int tid = threadIdx.x;
  const float* P = CLSP + (size_t)bh * NCHUNK * CLS_STRIDE;

  float M = -1e30f;
  #pragma unroll
  for (int c = 0; c < NCHUNK; ++c) M = fmaxf(M, P[c * CLS_STRIDE + 192]);
  float L = 0.f;
  float w[NCHUNK];
  #pragma unroll
  for (int c = 0; c < NCHUNK; ++c) {
    w[c] = expf(P[c * CLS_STRIDE + 192] - M);
    L += P[c * CLS_STRIDE + 193] * w[c];
  }
  if (tid < D3) {
    float acc = 0.f;
    #pragma unroll
    for (int c = 0; c < NCHUNK; ++c)
      acc = fmaf(w[c], P[c * CLS_STRIDE + tid], acc);
    const int b = bh / H_, h = bh % H_;
    FULL9b[((size_t)b * 9 + 0) * NCOL + h * D3 + tid] = (bf16_t)(acc / L);
  }
}

// ---------------- temporal attention per (b, h, patch), bf16 ----------------
// q from XQ, k from XV (swapped!), v from XK (swapped!). Writes bf16 T1U.
__global__ __launch_bounds__(64) void temporal_kernel(
    const bf16_t* __restrict__ XQ, const bf16_t* __restrict__ XK,
    const bf16_t* __restrict__ XV, bf16_t* __restrict__ T1U, int b0) {
  const int id = blockIdx.x;
  const int pi = id % P1;
  const int h  = (id / P1) % H_;
  const int bl = id / (P1 * H_);
  const int b  = b0 + bl;
  __shared__ float qs[8][196], ks[8][196];
  const int tid = threadIdx.x;  // 64

  #pragma unroll
  for (int i = 0; i < 6; ++i) {
    const int idx = tid + 64 * i;   // 0..383: [0,192) -> qs, [192,384) -> ks
    const int arr = idx / 192;
    const int c = idx % 192;        // chunk of 8 dims
    const int f = c / 24, d0 = (c % 24) * 8;
    const size_t base = ((size_t)bl * SEQ + (size_t)f * NP + pi + 2) * NCOL + h * D3 + d0;
    const bf16x8 v8 = arr ? *(const bf16x8*)(XV + base)   // keys from Wv proj
                          : *(const bf16x8*)(XQ + base);
    float* dst = arr ? &ks[f][d0] : &qs[f][d0];
    #pragma unroll
    for (int m2 = 0; m2 < 8; ++m2) dst[m2] = (float)v8[m2];
  }
  __syncthreads();

  const int f = tid >> 3, g = tid & 7;
  float s = 0.f;
  for (int d = 0; d < D3; d += 4) {
    const float4 a4 = *(const float4*)&qs[f][d];
    const float4 b4 = *(const float4*)&ks[g][d];
    s = fmaf(a4.x, b4.x, s); s = fmaf(a4.y, b4.y, s);
    s = fmaf(a4.z, b4.z, s); s = fmaf(a4.w, b4.w, s);
  }
  s *= RSCALE;

  float m = s;
  #pragma unroll
  for (int o = 1; o < 8; o <<= 1) m = fmaxf(m, __shfl_xor(m, o, 64));
  const float e = expf(s - m);
  float sum = e;
  #pragma unroll
  for (int o = 1; o < 8; o <<= 1) sum += __shfl_xor(sum, o, 64);
  float a = e / sum;
  #pragma unroll
  for (int o = 8; o < 64; o <<= 1) a += __shfl_xor(a, o, 64);  // column sums
  float wg[8];
  #pragma unroll
  for (int gg = 0; gg < 8; ++gg) wg[gg] = __shfl(a, gg, 64);

  const size_t vrow = (size_t)bl * SEQ * NCOL + h * D3;
  #pragma unroll
  for (int i = 0; i < 3; ++i) {
    const int d = tid + 64 * i;
    float o = 0.f;
    #pragma unroll
    for (int gg = 0; gg < 8; ++gg) {
      const bf16_t vv = XK[vrow + ((size_t)gg * NP + pi + 2) * NCOL + d];  // values from Wk proj
      o = fmaf(wg[gg], (float)vv, o);
    }
    T1U[((size_t)b * P1 + pi) * NCOL + h * D3 + d] = (bf16_t)o;
  }
}

// ---------------- stage-2, xi = 1..7: 195(+dup row xi) queries over 8 keys ----
__global__ __launch_bounds__(256) void stage2_xi_kernel(
    const bf16_t* __restrict__ Q2b, const bf16_t* __restrict__ K2b,
    const float* __restrict__ V2U, bf16_t* __restrict__ FULL9b) {
  const int xi = 1 + blockIdx.x % 7;
  const int h  = (blockIdx.x / 7) % H_;
  const int b  = blockIdx.x / (7 * H_);
  __shared__ float Ks[8][196], Vs[8][196], Qs[32][196];
  __shared__ float Pp[32][8];
  const int tid = threadIdx.x;

  for (int idx = tid; idx < 192; idx += 256) {          // keys, 8 x 192 bf16
    const int k = idx / 24, d0 = (idx % 24) * 8;
    const bf16x8 v8 = *(const bf16x8*)(K2b + ((size_t)(b * P1 + xi + k)) * NCOL + h * D3 + d0);
    #pragma unroll
    for (int m2 = 0; m2 < 8; ++m2) Ks[k][d0 + m2] = (float)v8[m2];
  }
  for (int idx = tid; idx < 384; idx += 256) {          // values, fp32
    const int k = idx / 48, d0 = (idx % 48) * 4;
    *(float4*)&Vs[k][d0] =
        *(const float4*)(V2U + ((size_t)(b * P1 + xi + k)) * NCOL + h * D3 + d0);
  }

  float acc = 0.f;  // for d = tid (tid < 192)
  for (int c = 0; c < 7; ++c) {
    __syncthreads();
    for (int idx = tid; idx < 768; idx += 256) {        // 32 queries x 192 dims
      const int qr = idx / 24, d0 = (idx % 24) * 8;
      const int rq = c * 32 + qr;
      if (rq < P1) {
        const bf16x8 v8 = *(const bf16x8*)(Q2b + ((size_t)(b * P1 + rq)) * NCOL + h * D3 + d0);
        #pragma unroll
        for (int m2 = 0; m2 < 8; ++m2) Qs[qr][d0 + m2] = (float)v8[m2];
      } else {
        #pragma unroll
        for (int m2 = 0; m2 < 8; ++m2) Qs[qr][d0 + m2] = 0.f;
      }
    }
    __syncthreads();
    const int grp = tid >> 3, k = tid & 7;
    float dot = 0.f;
    for (int d = 0; d < D3; d += 4) {
      const float4 a4 = *(const float4*)&Qs[grp][d];
      const float4 b4 = *(const float4*)&Ks[k][d];
      dot = fmaf(a4.x, b4.x, dot); dot = fmaf(a4.y, b4.y, dot);
      dot = fmaf(a4.z, b4.z, dot); dot = fmaf(a4.w, b4.w, dot);
    }
    dot *= RSCALE;
    float m = dot;
    #pragma unroll
    for (int o = 1; o < 8; o <<= 1) m = fmaxf(m, __shfl_xor(m, o, 64));
    const float e = expf(dot - m);
    float s = e;
    #pragma unroll
    for (int o = 1; o < 8; o <<= 1) s += __shfl_xor(s, o, 64);
    Pp[grp][k] = e / s;
    __syncthreads();
    if (tid < D3) {
      #pragma unroll 4
      for (int g2 = 0; g2 < 32; ++g2) {
        const int rq2 = c * 32 + g2;
        if (rq2 < P1) {
          const float mult = (rq2 == xi) ? 2.f : 1.f;
          float o = 0.f;
          #pragma unroll
          for (int kk = 0; kk < 8; ++kk) o = fmaf(Pp[g2][kk], Vs[kk][tid], o);
          acc = fmaf(mult, o, acc);
        }
      }
    }
  }
  if (tid < D3)
    FULL9b[((size_t)b * 9 + 1 + xi) * NCOL + h * D3 + tid] = (bf16_t)acc;
}

// ---------------- broadcast OUT9 -> full output ----------------
__global__ __launch_bounds__(256) void bcast_kernel(
    const float* __restrict__ OUT9, float* __restrict__ out) {
  const int idx = blockIdx.x * 256 + threadIdx.x;  // over float4s
  const int total = B_ * SEQ * (DIMX / 4);
  if (idx >= total) return;
  const int d4 = idx % (DIMX / 4);
  const int bs = idx / (DIMX / 4);
  const int s = bs % SEQ;
  const int b = bs / SEQ;
  const int row = (s == 0) ? 0 : 1 + ((s - 1) & 7);
  ((float4*)out)[idx] = ((const float4*)OUT9)[(size_t)(b * 9 + row) * (DIMX / 4) + d4];
}

// ---------------- launch ----------------
extern "C" void kernel_launch(void* const* d_in, const int* in_sizes, int n_in,
                              void* d_out, int out_size, void* d_ws, size_t ws_size,
                              hipStream_t stream) {
  const float* x  = (const float*)d_in[0];
  const float* Wq = (const float*)d_in[1];
  const float* bq = (const float*)d_in[2];
  const float* Wk = (const float*)d_in[3];
  const float* bk = (const float*)d_in[4];
  const float* Wv = (const float*)d_in[5];
  const float* bv = (const float*)d_in[6];
  const float* Wt = (const float*)d_in[7];
  const float* bt = (const float*)d_in[8];
  const float* Wf = (const float*)d_in[9];
  const float* bf = (const float*)d_in[10];
  float* out = (float*)d_out;
  (void)in_sizes; (void)n_in; (void)out_size;

  char* ws = (char*)d_ws;
  size_t off = 0;
  auto alloc_f32 = [&](size_t elems) {
    size_t a = (off + 63) & ~(size_t)63;
    off = a + elems * sizeof(float);
    return (float*)(ws + a);
  };
  auto alloc_bf16 = [&](size_t elems) {
    size_t a = (off + 63) & ~(size_t)63;
    off = a + elems * sizeof(bf16_t);
    return (bf16_t*)(ws + a);
  };

  bf16_t* T1Ub   = alloc_bf16((size_t)B_ * P1 * NCOL);
  bf16_t* TIUb   = alloc_bf16((size_t)B_ * P1 * DIMX);
  bf16_t* Q2b    = alloc_bf16((size_t)B_ * P1 * NCOL);
  bf16_t* K2b    = alloc_bf16((size_t)B_ * P1 * NCOL);
  float*  V2U    = alloc_f32((size_t)B_ * P1 * NCOL);
  bf16_t* FULL9b = alloc_bf16((size_t)B_ * 9 * NCOL);
  float*  OUT9   = alloc_f32((size_t)B_ * 9 * DIMX);
  float*  Smat   = alloc_f32((size_t)B_ * H_ * P1 * P1);
  float*  CLSP   = alloc_f32((size_t)B_ * H_ * NCHUNK * CLS_STRIDE);
  bf16_t* WqT    = alloc_bf16((size_t)NCOL * DIMX);
  bf16_t* WkT    = alloc_bf16((size_t)NCOL * DIMX);
  bf16_t* WvT    = alloc_bf16((size_t)NCOL * DIMX);
  bf16_t* WtT    = alloc_bf16((size_t)DIMX * NCOL);
  bf16_t* WfT    = alloc_bf16((size_t)DIMX * NCOL);

  // chunked stage-1 buffers (bf16 now)
  const size_t remain = (ws_size > off) ? (ws_size - off) : 0;
  int Bc = 8;
  while (Bc > 1 &&
         (size_t)Bc * SEQ * (3 * NCOL + DIMX) * sizeof(bf16_t) + 512 > remain)
    Bc >>= 1;
  bf16_t* XQb = alloc_bf16((size_t)Bc * SEQ * NCOL);
  bf16_t* XKb = alloc_bf16((size_t)Bc * SEQ * NCOL);
  bf16_t* XVb = alloc_bf16((size_t)Bc * SEQ * NCOL);
  bf16_t* xb  = alloc_bf16((size_t)Bc * SEQ * DIMX);

  // ---- weight transposes (bf16)
  transpose_cast<<<dim3(NCOL / 32, DIMX / 32), 256, 0, stream>>>(Wq, WqT, DIMX, NCOL);
  transpose_cast<<<dim3(NCOL / 32, DIMX / 32), 256, 0, stream>>>(Wk, WkT, DIMX, NCOL);
  transpose_cast<<<dim3(NCOL / 32, DIMX / 32), 256, 0, stream>>>(Wv, WvT, DIMX, NCOL);
  transpose_cast<<<dim3(DIMX / 32, NCOL / 32), 256, 0, stream>>>(Wt, WtT, NCOL, DIMX);
  transpose_cast<<<dim3(DIMX / 32, NCOL / 32), 256, 0, stream>>>(Wf, WfT, NCOL, DIMX);

  // ---- stage 1 (chunked): cast x, bf16 GEMMs (bf16 out), cls + temporal
  for (int b0 = 0; b0 < B_; b0 += Bc) {
    const int Mrows = Bc * SEQ;
    const int n4 = Mrows * DIMX / 4;
    cast_f32_bf16<<<dim3((n4 + 255) / 256), 256, 0, stream>>>(
        x + (size_t)b0 * SEQ * DIMX, xb, n4);
    dim3 g1((Mrows + 127) / 128, NCOL / 128);
    gemm_mfma_bt<<<g1, 256, 0, stream>>>(xb, WqT, bq, XQb, Mrows, NCOL, DIMX, 1);
    gemm_mfma_bt<<<g1, 256, 0, stream>>>(xb, WkT, bk, XKb, Mrows, NCOL, DIMX, 1);
    gemm_mfma_bt<<<g1, 256, 0, stream>>>(xb, WvT, bv, XVb, Mrows, NCOL, DIMX, 1);
    cls_part_kernel<<<dim3(Bc * H_, NCHUNK), 256, 0, stream>>>(XQb, XKb, XVb, CLSP, b0);
    temporal_kernel<<<dim3(Bc * P1 * H_), 64, 0, stream>>>(XQb, XKb, XVb, T1Ub, b0);
  }
  cls_combine_kernel<<<dim3(B_ * H_), 256, 0, stream>>>(CLSP, FULL9b);

  // ---- ti = merge(t1u) @ Wt + bt  (bf16 out)
  {
    dim3 g((B_ * P1 + 127) / 128, DIMX / 128);
    gemm_mfma_bt<<<g, 256, 0, stream>>>(T1Ub, WtT, bt, TIUb, B_ * P1, DIMX, NCOL, 1);
  }
  // ---- q2 = ti@Wq (bf16), v2 = ti@Wk (fp32), k2 = ti@Wv (bf16)
  {
    dim3 g((B_ * P1 + 127) / 128, NCOL / 128);
    gemm_mfma_bt<<<g, 256, 0, stream>>>(TIUb, WqT, bq, Q2b, B_ * P1, NCOL, DIMX, 1);
    gemm_mfma_bt<<<g, 256, 0, stream>>>(TIUb, WkT, bk, V2U, B_ * P1, NCOL, DIMX, 0);
    gemm_mfma_bt<<<g, 256, 0, stream>>>(TIUb, WvT, bv, K2b, B_ * P1, NCOL, DIMX, 1);
  }

  // ---- stage-2 attentions -> FULL9 rows 1..8
  xi0_scores_mfma<<<dim3(2, 2, B_ * H_), 256, 0, stream>>>(Q2b, K2b, Smat);
  xi0_finish_kernel<<<dim3(B_ * H_), 256, 0, stream>>>(Smat, V2U, FULL9b);
  stage2_xi_kernel<<<dim3(B_ * H_ * 7), 256, 0, stream>>>(Q2b, K2b, V2U, FULL9b);

  // ---- final projection on the 9 unique rows per batch
  {
    dim3 g((B_ * 9 + 127) / 128, DIMX / 128);
    gemm_mfma_bt<<<g, 256, 0, stream>>>(FULL9b, WfT, bf, OUT9, B_ * 9, DIMX, NCOL, 0);
  }

  // ---- broadcast to the full (B, 1569, 768) output
  {
    const int total4 = B_ * SEQ * (DIMX / 4);
    bcast_kernel<<<dim3((total4 + 255) / 256), 256, 0, stream>>>(OUT9, out);
  }
}